// Round 2
// baseline (1319.266 us; speedup 1.0000x reference)
//
#include <hip/hip_runtime.h>

#define DI __device__ __forceinline__

typedef short s16x8 __attribute__((ext_vector_type(8)));
typedef short s16x4 __attribute__((ext_vector_type(4)));
typedef float f32x4 __attribute__((ext_vector_type(4)));

typedef __attribute__((address_space(1))) const unsigned int as1_cuint;
typedef __attribute__((address_space(3))) unsigned int as3_uint;

DI unsigned short f2bf(float f) {
  union { float f; unsigned int u; } v; v.f = f;
  unsigned int r = v.u + 0x7fffu + ((v.u >> 16) & 1u);
  return (unsigned short)(r >> 16);
}
DI float bf2f(unsigned short b) {
  union { unsigned int u; float f; } v; v.u = ((unsigned int)b) << 16;
  return v.f;
}

DI void gl_lds16(const void* g, void* l) {
  // direct global->LDS, 16B per lane; LDS dest is wave-uniform base (+lane*16 implicit)
  __builtin_amdgcn_global_load_lds((as1_cuint*)g, (as3_uint*)l, 16, 0, 0);
}

// ---------------- fp32 -> bf16 convert (grid-stride, float4) ----------------
__global__ __launch_bounds__(256) void cvt_f32_bf16(const float* __restrict__ src,
                                                    unsigned short* __restrict__ dst, int n4) {
  int i = blockIdx.x * blockDim.x + threadIdx.x;
  int stride = gridDim.x * blockDim.x;
  for (; i < n4; i += stride) {
    float4 v = ((const float4*)src)[i];
    ushort4 o = make_ushort4(f2bf(v.x), f2bf(v.y), f2bf(v.z), f2bf(v.w));
    ((ushort4*)dst)[i] = o;
  }
}

// ---------------- dual RMSNorm: x = rms(hs)*w1, h = rms(hs)*w2 (same variance) -------------
__global__ __launch_bounds__(256) void rmsnorm_dual(const float* __restrict__ hs,
                                                    const float* __restrict__ w1,
                                                    const float* __restrict__ w2,
                                                    unsigned short* __restrict__ xo,
                                                    unsigned short* __restrict__ ho) {
  const int D = 2048;
  int t = blockIdx.x, tid = threadIdx.x;
  const float* row = hs + (size_t)t * D;
  float4 a = ((const float4*)row)[tid * 2];
  float4 b = ((const float4*)row)[tid * 2 + 1];
  float ss = a.x * a.x + a.y * a.y + a.z * a.z + a.w * a.w +
             b.x * b.x + b.y * b.y + b.z * b.z + b.w * b.w;
#pragma unroll
  for (int off = 32; off; off >>= 1) ss += __shfl_xor(ss, off);
  __shared__ float red[4];
  int wave = tid >> 6, lane = tid & 63;
  if (lane == 0) red[wave] = ss;
  __syncthreads();
  float tot = red[0] + red[1] + red[2] + red[3];
  float inv = rsqrtf(tot / (float)D + 1e-6f);
  int base = tid * 8;
  float vals[8] = {a.x, a.y, a.z, a.w, b.x, b.y, b.z, b.w};
  float4 w1a = ((const float4*)(w1 + base))[0];
  float4 w1b = ((const float4*)(w1 + base))[1];
  float4 w2a = ((const float4*)(w2 + base))[0];
  float4 w2b = ((const float4*)(w2 + base))[1];
  float w1v[8] = {w1a.x, w1a.y, w1a.z, w1a.w, w1b.x, w1b.y, w1b.z, w1b.w};
  float w2v[8] = {w2a.x, w2a.y, w2a.z, w2a.w, w2b.x, w2b.y, w2b.z, w2b.w};
  unsigned short ox[8], oh[8];
#pragma unroll
  for (int j = 0; j < 8; ++j) {
    float n = vals[j] * inv;
    ox[j] = f2bf(n * w1v[j]);
    oh[j] = f2bf(n * w2v[j]);
  }
  ushort4* xp = (ushort4*)(xo + (size_t)t * D + base);
  ushort4* hp = (ushort4*)(ho + (size_t)t * D + base);
  xp[0] = make_ushort4(ox[0], ox[1], ox[2], ox[3]);
  xp[1] = make_ushort4(ox[4], ox[5], ox[6], ox[7]);
  hp[0] = make_ushort4(oh[0], oh[1], oh[2], oh[3]);
  hp[1] = make_ushort4(oh[4], oh[5], oh[6], oh[7]);
}

// ---------------- GEMM: C[M,N] = A[M,K] @ Bt[N,K]^T  (m97 structure) ----------------
#define E_NONE 0
#define E_RES 3

template <int EPI>
__global__ __launch_bounds__(256, 2) void gemm_bt(
    const unsigned short* __restrict__ Amat, const unsigned short* __restrict__ Bt,
    int N, int K,
    unsigned short* __restrict__ Cbf, float* __restrict__ Cf,
    const float* __restrict__ Res) {
  __shared__ __align__(16) unsigned short Al[128 * 32];
  __shared__ __align__(16) unsigned short Bl[128 * 32];
  int tid = threadIdx.x, wave = tid >> 6, lane = tid & 63;
  int nwg = gridDim.x, nbn = N >> 7;
  int wg = blockIdx.x;
  int cpx = nwg >> 3;  // all launches have nwg % 8 == 0 -> bijective XCD swizzle
  int swz = (wg & 7) * cpx + (wg >> 3);
  int tm = swz / nbn, tn = swz - tm * nbn;
  size_t m0 = (size_t)tm * 128, n0 = (size_t)tn * 128;
  int wm = wave >> 1, wn = wave & 1;
  int lrow = lane & 15, lk8 = (lane >> 4) * 8;
  f32x4 acc[4][4] = {};

  for (int kt = 0; kt < K; kt += 32) {
    __syncthreads();
#pragma unroll
    for (int j = 0; j < 2; ++j) {
      int c = j * 256 + tid;
      int r = c >> 2, k8 = (c & 3) * 8;
      gl_lds16(Amat + (m0 + r) * (size_t)K + kt + k8, &Al[(size_t)(j * 256 + wave * 64) * 8]);
      gl_lds16(Bt + (n0 + r) * (size_t)K + kt + k8, &Bl[(size_t)(j * 256 + wave * 64) * 8]);
    }
    __syncthreads();
    s16x8 af[4], bfr[4];
#pragma unroll
    for (int mi = 0; mi < 4; ++mi)
      af[mi] = *(const s16x8*)&Al[(wm * 64 + mi * 16 + lrow) * 32 + lk8];
#pragma unroll
    for (int ni = 0; ni < 4; ++ni)
      bfr[ni] = *(const s16x8*)&Bl[(wn * 64 + ni * 16 + lrow) * 32 + lk8];
#pragma unroll
    for (int mi = 0; mi < 4; ++mi)
#pragma unroll
      for (int ni = 0; ni < 4; ++ni)
        acc[mi][ni] = __builtin_amdgcn_mfma_f32_16x16x32_bf16(af[mi], bfr[ni], acc[mi][ni], 0, 0, 0);
  }

#pragma unroll
  for (int mi = 0; mi < 4; ++mi) {
#pragma unroll
    for (int r = 0; r < 4; ++r) {
      int lr = wm * 64 + mi * 16 + (lane >> 4) * 4 + r;
      size_t row = m0 + lr;
#pragma unroll
      for (int ni = 0; ni < 4; ++ni) {
        int lc = wn * 64 + ni * 16 + lrow;
        size_t col = n0 + lc;
        float v = acc[mi][ni][r];
        if constexpr (EPI == E_RES) {
          Cf[row * N + col] = Res[row * N + col] + v;
        } else {
          Cbf[row * N + col] = f2bf(v);
        }
      }
    }
  }
}

// ------- fused MLP: Out = silu(H@Wg^T + c@Bsm) * (H@Wu^T)   [N=8192, K=2048] -------
__global__ __launch_bounds__(256, 2) void gemm_mlp(
    const unsigned short* __restrict__ Hm, const unsigned short* __restrict__ Wg,
    const unsigned short* __restrict__ Wu,
    const float* __restrict__ cvec, const float* __restrict__ Bsm,
    unsigned short* __restrict__ Out) {
  const int N = 8192, K = 2048;
  __shared__ __align__(16) unsigned short Al[128 * 32];
  __shared__ __align__(16) unsigned short Bg[128 * 32];
  __shared__ __align__(16) unsigned short Bu[128 * 32];
  int tid = threadIdx.x, wave = tid >> 6, lane = tid & 63;
  int nwg = gridDim.x, nbn = N >> 7;
  int wg = blockIdx.x;
  int cpx = nwg >> 3;
  int swz = (wg & 7) * cpx + (wg >> 3);
  int tm = swz / nbn, tn = swz - tm * nbn;
  size_t m0 = (size_t)tm * 128, n0 = (size_t)tn * 128;
  int wm = wave >> 1, wn = wave & 1;
  int lrow = lane & 15, lk8 = (lane >> 4) * 8;
  f32x4 ag[4][4] = {}, au[4][4] = {};

  for (int kt = 0; kt < K; kt += 32) {
    __syncthreads();
#pragma unroll
    for (int j = 0; j < 2; ++j) {
      int c = j * 256 + tid;
      int r = c >> 2, k8 = (c & 3) * 8;
      gl_lds16(Hm + (m0 + r) * (size_t)K + kt + k8, &Al[(size_t)(j * 256 + wave * 64) * 8]);
      gl_lds16(Wg + (n0 + r) * (size_t)K + kt + k8, &Bg[(size_t)(j * 256 + wave * 64) * 8]);
      gl_lds16(Wu + (n0 + r) * (size_t)K + kt + k8, &Bu[(size_t)(j * 256 + wave * 64) * 8]);
    }
    __syncthreads();
    s16x8 af[4], bg[4], bu[4];
#pragma unroll
    for (int mi = 0; mi < 4; ++mi)
      af[mi] = *(const s16x8*)&Al[(wm * 64 + mi * 16 + lrow) * 32 + lk8];
#pragma unroll
    for (int ni = 0; ni < 4; ++ni) {
      bg[ni] = *(const s16x8*)&Bg[(wn * 64 + ni * 16 + lrow) * 32 + lk8];
      bu[ni] = *(const s16x8*)&Bu[(wn * 64 + ni * 16 + lrow) * 32 + lk8];
    }
#pragma unroll
    for (int mi = 0; mi < 4; ++mi)
#pragma unroll
      for (int ni = 0; ni < 4; ++ni) {
        ag[mi][ni] = __builtin_amdgcn_mfma_f32_16x16x32_bf16(af[mi], bg[ni], ag[mi][ni], 0, 0, 0);
        au[mi][ni] = __builtin_amdgcn_mfma_f32_16x16x32_bf16(af[mi], bu[ni], au[mi][ni], 0, 0, 0);
      }
  }

  // epilogue: load c-tile (128x16 f32) and B-tile (16x128 f32) into reused LDS
  __syncthreads();
  float* cl = (float*)Al;
  float* bl = (float*)Bg;
#pragma unroll
  for (int j = 0; j < 2; ++j) {
    int fi = tid * 2 + j;  // float4 index 0..511
    ((float4*)cl)[fi] = ((const float4*)(cvec + m0 * 16))[fi];
    ((float4*)bl)[fi] = *(const float4*)(Bsm + (size_t)(fi >> 5) * N + n0 + (fi & 31) * 4);
  }
  __syncthreads();

#pragma unroll
  for (int mi = 0; mi < 4; ++mi) {
#pragma unroll
    for (int r = 0; r < 4; ++r) {
      int lr = wm * 64 + mi * 16 + (lane >> 4) * 4 + r;
      size_t row = m0 + lr;
#pragma unroll
      for (int ni = 0; ni < 4; ++ni) {
        int lc = wn * 64 + ni * 16 + lrow;
        size_t col = n0 + lc;
        float s = 0.f;
#pragma unroll
        for (int jj = 0; jj < 16; ++jj) s += cl[lr * 16 + jj] * bl[jj * 128 + lc];
        float g = ag[mi][ni][r] + s;
        float sig = 1.f / (1.f + __expf(-g));
        Out[row * N + col] = f2bf(g * sig * au[mi][ni][r]);
      }
    }
  }
}

// ---------------- causal flash attention (qkv packed [T,6144], heads of 128) -------------
__global__ __launch_bounds__(256, 2) void attn_fwd(const unsigned short* __restrict__ qkv,
                                                   unsigned short* __restrict__ attn) {
  const int S = 2048, LD = 6144;
  __shared__ __align__(16) unsigned short Kl[32 * 128];
  __shared__ __align__(16) unsigned short Vt[128 * 36];  // transposed, padded stride 36
  __shared__ __align__(16) unsigned short Pl[4 * 16 * 32];
  int tid = threadIdx.x, wave = tid >> 6, lane = tid & 63;
  int qt = blockIdx.x;               // 0..31 (64-row q tiles)
  int b = blockIdx.y >> 4, h = blockIdx.y & 15;
  int lrow = lane & 15, lk8 = (lane >> 4) * 8;
  const unsigned short* Qb = qkv + (size_t)b * S * LD + h * 128;
  const unsigned short* Kb = Qb + 2048;
  const unsigned short* Vb = Qb + 4096;
  int wq0 = qt * 64 + wave * 16;
  s16x8 qf[4];
#pragma unroll
  for (int kc = 0; kc < 4; ++kc)
    qf[kc] = *(const s16x8*)(Qb + (size_t)(wq0 + lrow) * LD + kc * 32 + lk8);
  f32x4 ao[8] = {};
  float m_r[4], l_r[4];
#pragma unroll
  for (int r = 0; r < 4; ++r) { m_r[r] = -1e30f; l_r[r] = 0.f; }
  const float scale = 0.08838834764831845f;  // 1/sqrt(128)
  int nkt = (qt + 1) * 2;
  for (int kt = 0; kt < nkt; ++kt) {
    int k0 = kt * 32;
    __syncthreads();
#pragma unroll
    for (int j = 0; j < 2; ++j) {
      int c = j * 256 + tid;
      int kr = c >> 4, d8 = (c & 15) * 8;
      gl_lds16(Kb + (size_t)(k0 + kr) * LD + d8, &Kl[(j * 256 + wave * 64) * 8]);
    }
#pragma unroll
    for (int j = 0; j < 2; ++j) {
      int c = j * 256 + tid;
      int kr = c >> 4, d8 = (c & 15) * 8;
      s16x8 vv = *(const s16x8*)(Vb + (size_t)(k0 + kr) * LD + d8);
#pragma unroll
      for (int e = 0; e < 8; ++e) Vt[(d8 + e) * 36 + kr] = (unsigned short)vv[e];
    }
    __syncthreads();
    f32x4 sa[2] = {};
#pragma unroll
    for (int ni = 0; ni < 2; ++ni)
#pragma unroll
      for (int kc = 0; kc < 4; ++kc) {
        s16x8 kf = *(const s16x8*)&Kl[(ni * 16 + lrow) * 128 + kc * 32 + lk8];
        sa[ni] = __builtin_amdgcn_mfma_f32_16x16x32_bf16(qf[kc], kf, sa[ni], 0, 0, 0);
      }
#pragma unroll
    for (int ni = 0; ni < 2; ++ni)
#pragma unroll
      for (int r = 0; r < 4; ++r) {
        int q_idx = wq0 + (lane >> 4) * 4 + r;
        int k_idx = k0 + ni * 16 + lrow;
        float sv = sa[ni][r] * scale;
        sa[ni][r] = (k_idx > q_idx) ? -1e30f : sv;
      }
    float mt[4];
#pragma unroll
    for (int r = 0; r < 4; ++r) mt[r] = fmaxf(sa[0][r], sa[1][r]);
#pragma unroll
    for (int r = 0; r < 4; ++r)
#pragma unroll
      for (int off = 8; off; off >>= 1) mt[r] = fmaxf(mt[r], __shfl_xor(mt[r], off));
    float al[4];
#pragma unroll
    for (int r = 0; r < 4; ++r) {
      float mn = fmaxf(m_r[r], mt[r]);
      al[r] = __expf(m_r[r] - mn);
      m_r[r] = mn;
    }
    float rs[4] = {0.f, 0.f, 0.f, 0.f};
#pragma unroll
    for (int ni = 0; ni < 2; ++ni)
#pragma unroll
      for (int r = 0; r < 4; ++r) {
        float p = __expf(sa[ni][r] - m_r[r]);
        rs[r] += p;
        Pl[wave * 512 + ((lane >> 4) * 4 + r) * 32 + ni * 16 + lrow] = f2bf(p);
      }
#pragma unroll
    for (int r = 0; r < 4; ++r) {
#pragma unroll
      for (int off = 8; off; off >>= 1) rs[r] += __shfl_xor(rs[r], off);
      l_r[r] = l_r[r] * al[r] + rs[r];
    }
#pragma unroll
    for (int df = 0; df < 8; ++df)
#pragma unroll
      for (int r = 0; r < 4; ++r) ao[df][r] *= al[r];
    asm volatile("s_waitcnt lgkmcnt(0)" ::: "memory");
    __builtin_amdgcn_sched_barrier(0);
    s16x8 pf = *(const s16x8*)&Pl[wave * 512 + lrow * 32 + lk8];
#pragma unroll
    for (int df = 0; df < 8; ++df) {
      const unsigned short* vp = &Vt[(df * 16 + lrow) * 36 + lk8];
      s16x4 v0 = *(const s16x4*)vp;
      s16x4 v1 = *(const s16x4*)(vp + 4);
      s16x8 vf = {v0[0], v0[1], v0[2], v0[3], v1[0], v1[1], v1[2], v1[3]};
      ao[df] = __builtin_amdgcn_mfma_f32_16x16x32_bf16(pf, vf, ao[df], 0, 0, 0);
    }
  }
#pragma unroll
  for (int df = 0; df < 8; ++df)
#pragma unroll
    for (int r = 0; r < 4; ++r) {
      int q = wq0 + (lane >> 4) * 4 + r;
      float v = ao[df][r] / l_r[r];
      attn[((size_t)b * S + q) * 2048 + h * 128 + df * 16 + lrow] = f2bf(v);
    }
}

// ---------------- c[t,r] = 0.1*tanh(attnO[t,:]@A[:,r]) * (h[t,:]@A[:,r]) ----------------
__global__ __launch_bounds__(256) void modc(const unsigned short* __restrict__ attnO,
                                            const unsigned short* __restrict__ h,
                                            const float* __restrict__ A,
                                            float* __restrict__ cvec) {
  const int D = 2048;
  int t = blockIdx.x * 4 + (threadIdx.x >> 6);
  int lane = threadIdx.x & 63;
  float aA[16] = {}, aH[16] = {};
  for (int i = 0; i < D / 64; ++i) {
    int d = i * 64 + lane;
    float av = bf2f(attnO[(size_t)t * D + d]);
    float hv = bf2f(h[(size_t)t * D + d]);
    const float* ar = A + (size_t)d * 16;
#pragma unroll
    for (int j = 0; j < 16; ++j) {
      float a = ar[j];
      aA[j] += av * a;
      aH[j] += hv * a;
    }
  }
#pragma unroll
  for (int j = 0; j < 16; ++j) {
#pragma unroll
    for (int off = 32; off; off >>= 1) {
      aA[j] += __shfl_xor(aA[j], off);
      aH[j] += __shfl_xor(aH[j], off);
    }
  }
#pragma unroll
  for (int j = 0; j < 16; ++j)
    if (lane == j) cvec[(size_t)t * 16 + j] = 0.1f * tanhf(aA[j]) * aH[j];
}

extern "C" void kernel_launch(void* const* d_in, const int* in_sizes, int n_in,
                              void* d_out, int out_size, void* d_ws, size_t ws_size,
                              hipStream_t stream) {
  const float* hs  = (const float*)d_in[0];
  const float* ln1 = (const float*)d_in[1];
  const float* ln2 = (const float*)d_in[2];
  const float* Wq  = (const float*)d_in[3];
  const float* Wk  = (const float*)d_in[4];
  const float* Wv  = (const float*)d_in[5];
  const float* Wo  = (const float*)d_in[6];
  const float* Am  = (const float*)d_in[7];
  const float* Bm  = (const float*)d_in[8];
  const float* Win = (const float*)d_in[9];
  const float* Wup = (const float*)d_in[10];
  const float* Wdn = (const float*)d_in[11];
  float* out = (float*)d_out;
  (void)in_sizes; (void)n_in;

  const int T = 4096;  // B*S
  const int Dm = 2048, F = 8192;
  const size_t MB = (size_t)1 << 20;

  // Lifetime-aliased workspace layout (184 MiB peak):
  //  [0,64)    tb (step 9+)     | earlier: wqkv@0(24), xb@24(16), attnO@40(16)
  //  [64,120)  qkv@64(48), wo@112(8) | later: win@64(32)
  //  [120,136) hb
  //  [136,152) attn | later: cv@136
  //  [152,184) wup  | later: wdn
  const size_t need = 184 * MB;
  if (ws_size < need) {  // diagnostic fallback: clean absmax failure instead of OOB abort
    hipMemsetAsync(d_out, 0, (size_t)out_size * 4, stream);
    return;
  }
  char* base = (char*)d_ws;
  unsigned short* tb    = (unsigned short*)(base);
  unsigned short* wqkv  = (unsigned short*)(base);
  unsigned short* xb    = (unsigned short*)(base + 24 * MB);
  unsigned short* attnO = (unsigned short*)(base + 40 * MB);
  unsigned short* qkv   = (unsigned short*)(base + 64 * MB);
  unsigned short* win   = (unsigned short*)(base + 64 * MB);
  unsigned short* wo    = (unsigned short*)(base + 112 * MB);
  unsigned short* hb    = (unsigned short*)(base + 120 * MB);
  unsigned short* attn  = (unsigned short*)(base + 136 * MB);
  float*          cv    = (float*)(base + 136 * MB);
  unsigned short* wup   = (unsigned short*)(base + 152 * MB);
  unsigned short* wdn   = (unsigned short*)(base + 152 * MB);

  // 1. QKV weight convert + norms
  cvt_f32_bf16<<<2048, 256, 0, stream>>>(Wq, wqkv, Dm * Dm / 4);
  cvt_f32_bf16<<<2048, 256, 0, stream>>>(Wk, wqkv + (size_t)Dm * Dm, Dm * Dm / 4);
  cvt_f32_bf16<<<2048, 256, 0, stream>>>(Wv, wqkv + (size_t)2 * Dm * Dm, Dm * Dm / 4);
  cvt_f32_bf16<<<2048, 256, 0, stream>>>(Wo, wo, Dm * Dm / 4);
  rmsnorm_dual<<<T, 256, 0, stream>>>(hs, ln1, ln2, xb, hb);

  // 2. QKV projection: (T x 2048) @ (6144 x 2048)^T -> qkv
  gemm_bt<E_NONE><<<(T / 128) * (3 * Dm / 128), 256, 0, stream>>>(
      xb, wqkv, 3 * Dm, Dm, qkv, nullptr, nullptr);

  // 3. attention
  attn_fwd<<<dim3(32, 32), 256, 0, stream>>>(qkv, attn);

  // 4. O projection -> attnO
  gemm_bt<E_NONE><<<(T / 128) * (Dm / 128), 256, 0, stream>>>(
      attn, wo, Dm, Dm, attnO, nullptr, nullptr);

  // 5. c[t,r]
  modc<<<T / 4, 256, 0, stream>>>(attnO, hb, Am, cv);

  // 6. MLP weight converts (into now-dead slots)
  cvt_f32_bf16<<<2048, 256, 0, stream>>>(Win, win, F * Dm / 4);
  cvt_f32_bf16<<<2048, 256, 0, stream>>>(Wup, wup, F * Dm / 4);

  // 7. fused gate/up: tb = silu(h@Win^T + c@B) * (h@Wup^T)
  gemm_mlp<<<(T / 128) * (F / 128), 256, 0, stream>>>(hb, win, wup, cv, Bm, tb);

  // 8. down weight convert (into wup's dead slot), then down GEMM with residual
  cvt_f32_bf16<<<2048, 256, 0, stream>>>(Wdn, wdn, Dm * F / 4);
  gemm_bt<E_RES><<<(T / 128) * (Dm / 128), 256, 0, stream>>>(
      tb, wdn, Dm, F, nullptr, out, hs);
}

// Round 3
// 1126.516 us; speedup vs baseline: 1.1711x; 1.1711x over previous
//
#include <hip/hip_runtime.h>

#define DI __device__ __forceinline__

typedef short s16x8 __attribute__((ext_vector_type(8)));
typedef short s16x4 __attribute__((ext_vector_type(4)));
typedef float f32x4 __attribute__((ext_vector_type(4)));

typedef __attribute__((address_space(1))) const unsigned int as1_cuint;
typedef __attribute__((address_space(3))) unsigned int as3_uint;

DI unsigned short f2bf(float f) {
  union { float f; unsigned int u; } v; v.f = f;
  unsigned int r = v.u + 0x7fffu + ((v.u >> 16) & 1u);
  return (unsigned short)(r >> 16);
}
DI float bf2f(unsigned short b) {
  union { unsigned int u; float f; } v; v.u = ((unsigned int)b) << 16;
  return v.f;
}

DI void gl_lds16(const void* g, void* l) {
  __builtin_amdgcn_global_load_lds((as1_cuint*)g, (as3_uint*)l, 16, 0, 0);
}

DI void bar() {
  __builtin_amdgcn_sched_barrier(0);
  __builtin_amdgcn_s_barrier();
  __builtin_amdgcn_sched_barrier(0);
}
DI void s_vmcnt6() { asm volatile("s_waitcnt vmcnt(6)" ::: "memory"); }
DI void s_vmcnt0() { asm volatile("s_waitcnt vmcnt(0)" ::: "memory"); }

// stage one 128x64 bf16 half-tile (16 KiB) linearly into LDS, with the
// XOR-swizzle applied on the GLOBAL source (rule #21: linear dest + inv-swz src).
DI void stage_half(const unsigned short* gb, size_t r0, int K, int kt,
                   unsigned short* lh, int tid) {
#pragma unroll
  for (int j = 0; j < 2; ++j) {
    int o = j * 8192 + tid * 16;  // byte offset in half-tile
    int row = o >> 7, cb = o & 127;
    int scb = cb ^ ((row & 7) << 4);
    gl_lds16(gb + (r0 + row) * (size_t)K + kt + (scb >> 1),
             lh + ((j * 8192 + (tid >> 6) * 1024) >> 1));
  }
}

// read one MFMA fragment (16B/lane) from a swizzled half-tile
DI s16x8 rd_frag(const unsigned short* lds, int baseE, int rwh, int kh, int lane) {
  int cb = kh * 64 + ((lane >> 4) << 4);
  int scb = cb ^ ((rwh & 7) << 4);
  return *(const s16x8*)&lds[baseE + rwh * 64 + (scb >> 1)];
}

// ---------------- fp32 -> bf16 convert ----------------
__global__ __launch_bounds__(256) void cvt_f32_bf16(const float* __restrict__ src,
                                                    unsigned short* __restrict__ dst, int n4) {
  int i = blockIdx.x * blockDim.x + threadIdx.x;
  int stride = gridDim.x * blockDim.x;
  for (; i < n4; i += stride) {
    float4 v = ((const float4*)src)[i];
    ((ushort4*)dst)[i] = make_ushort4(f2bf(v.x), f2bf(v.y), f2bf(v.z), f2bf(v.w));
  }
}

// ---------------- dual RMSNorm ----------------
__global__ __launch_bounds__(256) void rmsnorm_dual(const float* __restrict__ hs,
                                                    const float* __restrict__ w1,
                                                    const float* __restrict__ w2,
                                                    unsigned short* __restrict__ xo,
                                                    unsigned short* __restrict__ ho) {
  const int D = 2048;
  int t = blockIdx.x, tid = threadIdx.x;
  const float* row = hs + (size_t)t * D;
  float4 a = ((const float4*)row)[tid * 2];
  float4 b = ((const float4*)row)[tid * 2 + 1];
  float ss = a.x * a.x + a.y * a.y + a.z * a.z + a.w * a.w +
             b.x * b.x + b.y * b.y + b.z * b.z + b.w * b.w;
#pragma unroll
  for (int off = 32; off; off >>= 1) ss += __shfl_xor(ss, off);
  __shared__ float red[4];
  int wave = tid >> 6, lane = tid & 63;
  if (lane == 0) red[wave] = ss;
  __syncthreads();
  float tot = red[0] + red[1] + red[2] + red[3];
  float inv = rsqrtf(tot / (float)D + 1e-6f);
  int base = tid * 8;
  float vals[8] = {a.x, a.y, a.z, a.w, b.x, b.y, b.z, b.w};
  float4 w1a = ((const float4*)(w1 + base))[0];
  float4 w1b = ((const float4*)(w1 + base))[1];
  float4 w2a = ((const float4*)(w2 + base))[0];
  float4 w2b = ((const float4*)(w2 + base))[1];
  float w1v[8] = {w1a.x, w1a.y, w1a.z, w1a.w, w1b.x, w1b.y, w1b.z, w1b.w};
  float w2v[8] = {w2a.x, w2a.y, w2a.z, w2a.w, w2b.x, w2b.y, w2b.z, w2b.w};
  unsigned short ox[8], oh[8];
#pragma unroll
  for (int j = 0; j < 8; ++j) {
    float n = vals[j] * inv;
    ox[j] = f2bf(n * w1v[j]);
    oh[j] = f2bf(n * w2v[j]);
  }
  ushort4* xp = (ushort4*)(xo + (size_t)t * D + base);
  ushort4* hp = (ushort4*)(ho + (size_t)t * D + base);
  xp[0] = make_ushort4(ox[0], ox[1], ox[2], ox[3]);
  xp[1] = make_ushort4(ox[4], ox[5], ox[6], ox[7]);
  hp[0] = make_ushort4(oh[0], oh[1], oh[2], oh[3]);
  hp[1] = make_ushort4(oh[4], oh[5], oh[6], oh[7]);
}

// =========== 256x256 8-phase GEMM (T2+T3+T4+T5): C[M,N] = A @ Bt^T -> bf16 ===========
// 8 waves (2M x 4N), per-wave C = 128x64 with M-frags at 32-row stride, N-frags at
// 16-col stride (half-tiles are phase-exclusive -> staging is race-free).
// LDS: 2 buf x 4 half-tiles (A0,A1,B0,B1) x 8192 elems = 128 KiB.
__global__ __launch_bounds__(512, 2) void gemm256(
    const unsigned short* __restrict__ Amat, const unsigned short* __restrict__ Bt,
    int N, int K, unsigned short* __restrict__ Cbf) {
  __shared__ __align__(16) unsigned short lds[65536];
  int tid = threadIdx.x, lane = tid & 63;
  int w = tid >> 6, wm = w >> 2, wn = w & 3;
  int lr = lane & 15, lkh = lane >> 4;
  int nbn = N >> 8, nwg = gridDim.x, wg = blockIdx.x;
  int cpx = nwg >> 3;
  int swz = (wg & 7) * cpx + (wg >> 3);
  int tm = swz / nbn, tn = swz - tm * nbn;
  size_t m0 = (size_t)tm * 256, n0 = (size_t)tn * 256;
  int NT = K >> 6;

  auto stage = [&](int tau, int slot) {  // slot: 0=A0 1=A1 2=B0 3=B1
    if (tau >= NT) return;
    const unsigned short* gb = (slot >= 2) ? Bt : Amat;
    size_t r0 = (slot >= 2) ? (n0 + (size_t)(slot - 2) * 128) : (m0 + (size_t)slot * 128);
    stage_half(gb, r0, K, tau * 64, &lds[(tau & 1) * 32768 + slot * 8192], tid);
  };

  // prologue: tile0 {A0,B0,A1,B1}, tile1 {A0,B0,A1}; leave 3 halves in flight
  stage(0, 0); stage(0, 2); stage(0, 1); stage(0, 3);
  stage(1, 0); stage(1, 2); stage(1, 1);
  s_vmcnt6();
  bar();

  f32x4 acc[8][4] = {};  // [mh*4+mi][nh*2+ni]
  s16x8 afr[4][2], bfr[2][2][2];

  for (int t = 0; t < NT; ++t) {
    int buf = (t & 1) * 32768;
    // ---- p0: (mh0, nh0) : read A0(8) + B0(4); stage B1(t+1)
#pragma unroll
    for (int mi = 0; mi < 4; ++mi)
#pragma unroll
      for (int kh = 0; kh < 2; ++kh)
        afr[mi][kh] = rd_frag(lds, buf + 0 * 8192, mi * 32 + wm * 16 + lr, kh, lane);
#pragma unroll
    for (int ni = 0; ni < 2; ++ni)
#pragma unroll
      for (int kh = 0; kh < 2; ++kh)
        bfr[0][ni][kh] = rd_frag(lds, buf + 2 * 8192, ni * 64 + wn * 16 + lr, kh, lane);
    stage(t + 1, 3);
    bar();
    __builtin_amdgcn_s_setprio(1);
#pragma unroll
    for (int mi = 0; mi < 4; ++mi)
#pragma unroll
      for (int ni = 0; ni < 2; ++ni)
#pragma unroll
        for (int kh = 0; kh < 2; ++kh)
          acc[mi][ni] = __builtin_amdgcn_mfma_f32_16x16x32_bf16(afr[mi][kh], bfr[0][ni][kh], acc[mi][ni], 0, 0, 0);
    __builtin_amdgcn_s_setprio(0);
    bar();
    // ---- p1: (mh0, nh1) : read B1(4); stage A0(t+2)
#pragma unroll
    for (int ni = 0; ni < 2; ++ni)
#pragma unroll
      for (int kh = 0; kh < 2; ++kh)
        bfr[1][ni][kh] = rd_frag(lds, buf + 3 * 8192, ni * 64 + wn * 16 + lr, kh, lane);
    stage(t + 2, 0);
    bar();
    __builtin_amdgcn_s_setprio(1);
#pragma unroll
    for (int mi = 0; mi < 4; ++mi)
#pragma unroll
      for (int ni = 0; ni < 2; ++ni)
#pragma unroll
        for (int kh = 0; kh < 2; ++kh)
          acc[mi][2 + ni] = __builtin_amdgcn_mfma_f32_16x16x32_bf16(afr[mi][kh], bfr[1][ni][kh], acc[mi][2 + ni], 0, 0, 0);
    __builtin_amdgcn_s_setprio(0);
    bar();
    // ---- p2: (mh1, nh0) : read A1(8); stage B0(t+2)
#pragma unroll
    for (int mi = 0; mi < 4; ++mi)
#pragma unroll
      for (int kh = 0; kh < 2; ++kh)
        afr[mi][kh] = rd_frag(lds, buf + 1 * 8192, mi * 32 + wm * 16 + lr, kh, lane);
    stage(t + 2, 2);
    bar();
    __builtin_amdgcn_s_setprio(1);
#pragma unroll
    for (int mi = 0; mi < 4; ++mi)
#pragma unroll
      for (int ni = 0; ni < 2; ++ni)
#pragma unroll
        for (int kh = 0; kh < 2; ++kh)
          acc[4 + mi][ni] = __builtin_amdgcn_mfma_f32_16x16x32_bf16(afr[mi][kh], bfr[0][ni][kh], acc[4 + mi][ni], 0, 0, 0);
    __builtin_amdgcn_s_setprio(0);
    bar();
    // ---- p3: (mh1, nh1) : no reads; stage A1(t+2); boundary vmcnt
    stage(t + 2, 1);
    bar();
    __builtin_amdgcn_s_setprio(1);
#pragma unroll
    for (int mi = 0; mi < 4; ++mi)
#pragma unroll
      for (int ni = 0; ni < 2; ++ni)
#pragma unroll
        for (int kh = 0; kh < 2; ++kh)
          acc[4 + mi][2 + ni] = __builtin_amdgcn_mfma_f32_16x16x32_bf16(afr[mi][kh], bfr[1][ni][kh], acc[4 + mi][2 + ni], 0, 0, 0);
    __builtin_amdgcn_s_setprio(0);
    if (t < NT - 2) s_vmcnt6();
    else if (t == NT - 2) s_vmcnt0();
    bar();
  }

#pragma unroll
  for (int mh = 0; mh < 2; ++mh)
#pragma unroll
    for (int mi = 0; mi < 4; ++mi)
#pragma unroll
      for (int r = 0; r < 4; ++r) {
        size_t row = m0 + mh * 128 + mi * 32 + wm * 16 + lkh * 4 + r;
#pragma unroll
        for (int nh = 0; nh < 2; ++nh)
#pragma unroll
          for (int ni = 0; ni < 2; ++ni) {
            size_t col = n0 + nh * 128 + ni * 64 + wn * 16 + lr;
            Cbf[row * N + col] = f2bf(acc[mh * 4 + mi][nh * 2 + ni][r]);
          }
      }
}

// ===== 256x128 8-phase fused MLP: Out = silu(H@Wg^T + c@Bsm) * (H@Wu^T), N=8192 K=2048 ====
// slots: 0=A0 1=A1 2=Bg 3=Bu (Bg/Bu are full 128-row tiles). Phases: (mh0,g),(mh0,u),(mh1,g),(mh1,u)
__global__ __launch_bounds__(512, 2) void gemm_mlp256(
    const unsigned short* __restrict__ Hm, const unsigned short* __restrict__ Wg,
    const unsigned short* __restrict__ Wu,
    const float* __restrict__ cvec, const float* __restrict__ Bsm,
    unsigned short* __restrict__ Out) {
  const int N = 8192, K = 2048, NT = K >> 6;
  __shared__ __align__(16) unsigned short lds[65536];
  int tid = threadIdx.x, lane = tid & 63;
  int w = tid >> 6, wm = w >> 2, wn = w & 3;
  int lr = lane & 15, lkh = lane >> 4;
  int nbn = N >> 7, nwg = gridDim.x, wg = blockIdx.x;
  int cpx = nwg >> 3;
  int swz = (wg & 7) * cpx + (wg >> 3);
  int tm = swz / nbn, tn = swz - tm * nbn;
  size_t m0 = (size_t)tm * 256, n0 = (size_t)tn * 128;

  auto stage = [&](int tau, int slot) {
    if (tau >= NT) return;
    const unsigned short* gb = (slot == 2) ? Wg : (slot == 3) ? Wu : Hm;
    size_t r0 = (slot >= 2) ? n0 : (m0 + (size_t)slot * 128);
    stage_half(gb, r0, K, tau * 64, &lds[(tau & 1) * 32768 + slot * 8192], tid);
  };

  stage(0, 0); stage(0, 2); stage(0, 1); stage(0, 3);
  stage(1, 0); stage(1, 2); stage(1, 1);
  s_vmcnt6();
  bar();

  f32x4 ag[8][2] = {}, au[8][2] = {};
  s16x8 afr[4][2], bg[2][2], bu[2][2];

  for (int t = 0; t < NT; ++t) {
    int buf = (t & 1) * 32768;
    // p0: (mh0, gate): read A0(8)+Bg(4); stage Bu(t+1)
#pragma unroll
    for (int mi = 0; mi < 4; ++mi)
#pragma unroll
      for (int kh = 0; kh < 2; ++kh)
        afr[mi][kh] = rd_frag(lds, buf + 0 * 8192, mi * 32 + wm * 16 + lr, kh, lane);
#pragma unroll
    for (int ni = 0; ni < 2; ++ni)
#pragma unroll
      for (int kh = 0; kh < 2; ++kh)
        bg[ni][kh] = rd_frag(lds, buf + 2 * 8192, ni * 64 + wn * 16 + lr, kh, lane);
    stage(t + 1, 3);
    bar();
    __builtin_amdgcn_s_setprio(1);
#pragma unroll
    for (int mi = 0; mi < 4; ++mi)
#pragma unroll
      for (int ni = 0; ni < 2; ++ni)
#pragma unroll
        for (int kh = 0; kh < 2; ++kh)
          ag[mi][ni] = __builtin_amdgcn_mfma_f32_16x16x32_bf16(afr[mi][kh], bg[ni][kh], ag[mi][ni], 0, 0, 0);
    __builtin_amdgcn_s_setprio(0);
    bar();
    // p1: (mh0, up): read Bu(4); stage A0(t+2)
#pragma unroll
    for (int ni = 0; ni < 2; ++ni)
#pragma unroll
      for (int kh = 0; kh < 2; ++kh)
        bu[ni][kh] = rd_frag(lds, buf + 3 * 8192, ni * 64 + wn * 16 + lr, kh, lane);
    stage(t + 2, 0);
    bar();
    __builtin_amdgcn_s_setprio(1);
#pragma unroll
    for (int mi = 0; mi < 4; ++mi)
#pragma unroll
      for (int ni = 0; ni < 2; ++ni)
#pragma unroll
        for (int kh = 0; kh < 2; ++kh)
          au[mi][ni] = __builtin_amdgcn_mfma_f32_16x16x32_bf16(afr[mi][kh], bu[ni][kh], au[mi][ni], 0, 0, 0);
    __builtin_amdgcn_s_setprio(0);
    bar();
    // p2: (mh1, gate): read A1(8); stage Bg(t+2)
#pragma unroll
    for (int mi = 0; mi < 4; ++mi)
#pragma unroll
      for (int kh = 0; kh < 2; ++kh)
        afr[mi][kh] = rd_frag(lds, buf + 1 * 8192, mi * 32 + wm * 16 + lr, kh, lane);
    stage(t + 2, 2);
    bar();
    __builtin_amdgcn_s_setprio(1);
#pragma unroll
    for (int mi = 0; mi < 4; ++mi)
#pragma unroll
      for (int ni = 0; ni < 2; ++ni)
#pragma unroll
        for (int kh = 0; kh < 2; ++kh)
          ag[4 + mi][ni] = __builtin_amdgcn_mfma_f32_16x16x32_bf16(afr[mi][kh], bg[ni][kh], ag[4 + mi][ni], 0, 0, 0);
    __builtin_amdgcn_s_setprio(0);
    bar();
    // p3: (mh1, up): no reads; stage A1(t+2); boundary vmcnt
    stage(t + 2, 1);
    bar();
    __builtin_amdgcn_s_setprio(1);
#pragma unroll
    for (int mi = 0; mi < 4; ++mi)
#pragma unroll
      for (int ni = 0; ni < 2; ++ni)
#pragma unroll
        for (int kh = 0; kh < 2; ++kh)
          au[4 + mi][ni] = __builtin_amdgcn_mfma_f32_16x16x32_bf16(afr[mi][kh], bu[ni][kh], au[4 + mi][ni], 0, 0, 0);
    __builtin_amdgcn_s_setprio(0);
    if (t < NT - 2) s_vmcnt6();
    else if (t == NT - 2) s_vmcnt0();
    bar();
  }

  // epilogue: c-tile 256x16 f32 (16KB) + Bsm-tile 16x128 f32 (8KB) into reused LDS
  float* cl = (float*)lds;          // [256][16]
  float* bl = (float*)&lds[32768];  // [16][128] (elems -> byte 65536? no: 32768 elems = 64KB base)
#pragma unroll
  for (int j = 0; j < 2; ++j) {
    int fi = tid * 2 + j;  // 0..1023 float4
    ((float4*)cl)[fi] = ((const float4*)(cvec + m0 * 16))[fi];
  }
  {
    int fi = tid;  // 0..511 float4 : bl[j][c4*4], j=fi>>5
    ((float4*)bl)[fi] = *(const float4*)(Bsm + (size_t)(fi >> 5) * N + n0 + (fi & 31) * 4);
  }
  bar();

#pragma unroll
  for (int mh = 0; mh < 2; ++mh)
#pragma unroll
    for (int mi = 0; mi < 4; ++mi)
#pragma unroll
      for (int r = 0; r < 4; ++r) {
        int rr = mh * 128 + mi * 32 + wm * 16 + lkh * 4 + r;
        size_t row = m0 + rr;
#pragma unroll
        for (int ni = 0; ni < 2; ++ni) {
          int cc = ni * 64 + wn * 16 + lr;
          size_t col = n0 + cc;
          float s = 0.f;
#pragma unroll
          for (int jj = 0; jj < 16; ++jj) s += cl[rr * 16 + jj] * bl[jj * 128 + cc];
          float g = ag[mh * 4 + mi][ni][r] + s;
          float sig = 1.f / (1.f + __expf(-g));
          Out[row * N + col] = f2bf(g * sig * au[mh * 4 + mi][ni][r]);
        }
      }
}

// ---------------- m97-structure 128x128 GEMM (kept for O-proj & down) ----------------
#define E_NONE 0
#define E_RES 3
template <int EPI>
__global__ __launch_bounds__(256, 2) void gemm_bt(
    const unsigned short* __restrict__ Amat, const unsigned short* __restrict__ Bt,
    int N, int K,
    unsigned short* __restrict__ Cbf, float* __restrict__ Cf,
    const float* __restrict__ Res) {
  __shared__ __align__(16) unsigned short Al[128 * 32];
  __shared__ __align__(16) unsigned short Bl[128 * 32];
  int tid = threadIdx.x, wave = tid >> 6, lane = tid & 63;
  int nwg = gridDim.x, nbn = N >> 7;
  int wg = blockIdx.x;
  int cpx = nwg >> 3;
  int swz = (wg & 7) * cpx + (wg >> 3);
  int tm = swz / nbn, tn = swz - tm * nbn;
  size_t m0 = (size_t)tm * 128, n0 = (size_t)tn * 128;
  int wm = wave >> 1, wn = wave & 1;
  int lrow = lane & 15, lk8 = (lane >> 4) * 8;
  f32x4 acc[4][4] = {};

  for (int kt = 0; kt < K; kt += 32) {
    __syncthreads();
#pragma unroll
    for (int j = 0; j < 2; ++j) {
      int c = j * 256 + tid;
      int r = c >> 2, k8 = (c & 3) * 8;
      gl_lds16(Amat + (m0 + r) * (size_t)K + kt + k8, &Al[(size_t)(j * 256 + wave * 64) * 8]);
      gl_lds16(Bt + (n0 + r) * (size_t)K + kt + k8, &Bl[(size_t)(j * 256 + wave * 64) * 8]);
    }
    __syncthreads();
    s16x8 af[4], bfr[4];
#pragma unroll
    for (int mi = 0; mi < 4; ++mi)
      af[mi] = *(const s16x8*)&Al[(wm * 64 + mi * 16 + lrow) * 32 + lk8];
#pragma unroll
    for (int ni = 0; ni < 4; ++ni)
      bfr[ni] = *(const s16x8*)&Bl[(wn * 64 + ni * 16 + lrow) * 32 + lk8];
#pragma unroll
    for (int mi = 0; mi < 4; ++mi)
#pragma unroll
      for (int ni = 0; ni < 4; ++ni)
        acc[mi][ni] = __builtin_amdgcn_mfma_f32_16x16x32_bf16(af[mi], bfr[ni], acc[mi][ni], 0, 0, 0);
  }

#pragma unroll
  for (int mi = 0; mi < 4; ++mi) {
#pragma unroll
    for (int r = 0; r < 4; ++r) {
      int lr = wm * 64 + mi * 16 + (lane >> 4) * 4 + r;
      size_t row = m0 + lr;
#pragma unroll
      for (int ni = 0; ni < 4; ++ni) {
        int lc = wn * 64 + ni * 16 + lrow;
        size_t col = n0 + lc;
        float v = acc[mi][ni][r];
        if constexpr (EPI == E_RES) {
          Cf[row * N + col] = Res[row * N + col] + v;
        } else {
          Cbf[row * N + col] = f2bf(v);
        }
      }
    }
  }
}

// ---------------- causal flash attention ----------------
__global__ __launch_bounds__(256, 2) void attn_fwd(const unsigned short* __restrict__ qkv,
                                                   unsigned short* __restrict__ attn) {
  const int S = 2048, LD = 6144;
  __shared__ __align__(16) unsigned short Kl[32 * 128];
  __shared__ __align__(16) unsigned short Vt[128 * 36];
  __shared__ __align__(16) unsigned short Pl[4 * 16 * 32];
  int tid = threadIdx.x, wave = tid >> 6, lane = tid & 63;
  int qt = blockIdx.x;
  int b = blockIdx.y >> 4, h = blockIdx.y & 15;
  int lrow = lane & 15, lk8 = (lane >> 4) * 8;
  const unsigned short* Qb = qkv + (size_t)b * S * LD + h * 128;
  const unsigned short* Kb = Qb + 2048;
  const unsigned short* Vb = Qb + 4096;
  int wq0 = qt * 64 + wave * 16;
  s16x8 qf[4];
#pragma unroll
  for (int kc = 0; kc < 4; ++kc)
    qf[kc] = *(const s16x8*)(Qb + (size_t)(wq0 + lrow) * LD + kc * 32 + lk8);
  f32x4 ao[8] = {};
  float m_r[4], l_r[4];
#pragma unroll
  for (int r = 0; r < 4; ++r) { m_r[r] = -1e30f; l_r[r] = 0.f; }
  const float scale = 0.08838834764831845f;
  int nkt = (qt + 1) * 2;
  for (int kt = 0; kt < nkt; ++kt) {
    int k0 = kt * 32;
    __syncthreads();
#pragma unroll
    for (int j = 0; j < 2; ++j) {
      int c = j * 256 + tid;
      int kr = c >> 4, d8 = (c & 15) * 8;
      gl_lds16(Kb + (size_t)(k0 + kr) * LD + d8, &Kl[(j * 256 + wave * 64) * 8]);
    }
#pragma unroll
    for (int j = 0; j < 2; ++j) {
      int c = j * 256 + tid;
      int kr = c >> 4, d8 = (c & 15) * 8;
      s16x8 vv = *(const s16x8*)(Vb + (size_t)(k0 + kr) * LD + d8);
#pragma unroll
      for (int e = 0; e < 8; ++e) Vt[(d8 + e) * 36 + kr] = (unsigned short)vv[e];
    }
    __syncthreads();
    f32x4 sa[2] = {};
#pragma unroll
    for (int ni = 0; ni < 2; ++ni)
#pragma unroll
      for (int kc = 0; kc < 4; ++kc) {
        s16x8 kf = *(const s16x8*)&Kl[(ni * 16 + lrow) * 128 + kc * 32 + lk8];
        sa[ni] = __builtin_amdgcn_mfma_f32_16x16x32_bf16(qf[kc], kf, sa[ni], 0, 0, 0);
      }
#pragma unroll
    for (int ni = 0; ni < 2; ++ni)
#pragma unroll
      for (int r = 0; r < 4; ++r) {
        int q_idx = wq0 + (lane >> 4) * 4 + r;
        int k_idx = k0 + ni * 16 + lrow;
        float sv = sa[ni][r] * scale;
        sa[ni][r] = (k_idx > q_idx) ? -1e30f : sv;
      }
    float mt[4];
#pragma unroll
    for (int r = 0; r < 4; ++r) mt[r] = fmaxf(sa[0][r], sa[1][r]);
#pragma unroll
    for (int r = 0; r < 4; ++r)
#pragma unroll
      for (int off = 8; off; off >>= 1) mt[r] = fmaxf(mt[r], __shfl_xor(mt[r], off));
    float al[4];
#pragma unroll
    for (int r = 0; r < 4; ++r) {
      float mn = fmaxf(m_r[r], mt[r]);
      al[r] = __expf(m_r[r] - mn);
      m_r[r] = mn;
    }
    float rs[4] = {0.f, 0.f, 0.f, 0.f};
#pragma unroll
    for (int ni = 0; ni < 2; ++ni)
#pragma unroll
      for (int r = 0; r < 4; ++r) {
        float p = __expf(sa[ni][r] - m_r[r]);
        rs[r] += p;
        Pl[wave * 512 + ((lane >> 4) * 4 + r) * 32 + ni * 16 + lrow] = f2bf(p);
      }
#pragma unroll
    for (int r = 0; r < 4; ++r) {
#pragma unroll
      for (int off = 8; off; off >>= 1) rs[r] += __shfl_xor(rs[r], off);
      l_r[r] = l_r[r] * al[r] + rs[r];
    }
#pragma unroll
    for (int df = 0; df < 8; ++df)
#pragma unroll
      for (int r = 0; r < 4; ++r) ao[df][r] *= al[r];
    asm volatile("s_waitcnt lgkmcnt(0)" ::: "memory");
    __builtin_amdgcn_sched_barrier(0);
    s16x8 pf = *(const s16x8*)&Pl[wave * 512 + lrow * 32 + lk8];
#pragma unroll
    for (int df = 0; df < 8; ++df) {
      const unsigned short* vp = &Vt[(df * 16 + lrow) * 36 + lk8];
      s16x4 v0 = *(const s16x4*)vp;
      s16x4 v1 = *(const s16x4*)(vp + 4);
      s16x8 vf = {v0[0], v0[1], v0[2], v0[3], v1[0], v1[1], v1[2], v1[3]};
      ao[df] = __builtin_amdgcn_mfma_f32_16x16x32_bf16(pf, vf, ao[df], 0, 0, 0);
    }
  }
#pragma unroll
  for (int df = 0; df < 8; ++df)
#pragma unroll
    for (int r = 0; r < 4; ++r) {
      int q = wq0 + (lane >> 4) * 4 + r;
      float v = ao[df][r] / l_r[r];
      attn[((size_t)b * S + q) * 2048 + h * 128 + df * 16 + lrow] = f2bf(v);
    }
}

// ---------------- modc ----------------
__global__ __launch_bounds__(256) void modc(const unsigned short* __restrict__ attnO,
                                            const unsigned short* __restrict__ h,
                                            const float* __restrict__ A,
                                            float* __restrict__ cvec) {
  const int D = 2048;
  int t = blockIdx.x * 4 + (threadIdx.x >> 6);
  int lane = threadIdx.x & 63;
  float aA[16] = {}, aH[16] = {};
  for (int i = 0; i < D / 64; ++i) {
    int d = i * 64 + lane;
    float av = bf2f(attnO[(size_t)t * D + d]);
    float hv = bf2f(h[(size_t)t * D + d]);
    const float* ar = A + (size_t)d * 16;
#pragma unroll
    for (int j = 0; j < 16; ++j) {
      float a = ar[j];
      aA[j] += av * a;
      aH[j] += hv * a;
    }
  }
#pragma unroll
  for (int j = 0; j < 16; ++j) {
#pragma unroll
    for (int off = 32; off; off >>= 1) {
      aA[j] += __shfl_xor(aA[j], off);
      aH[j] += __shfl_xor(aH[j], off);
    }
  }
#pragma unroll
  for (int j = 0; j < 16; ++j)
    if (lane == j) cvec[(size_t)t * 16 + j] = 0.1f * tanhf(aA[j]) * aH[j];
}

extern "C" void kernel_launch(void* const* d_in, const int* in_sizes, int n_in,
                              void* d_out, int out_size, void* d_ws, size_t ws_size,
                              hipStream_t stream) {
  const float* hs  = (const float*)d_in[0];
  const float* ln1 = (const float*)d_in[1];
  const float* ln2 = (const float*)d_in[2];
  const float* Wq  = (const float*)d_in[3];
  const float* Wk  = (const float*)d_in[4];
  const float* Wv  = (const float*)d_in[5];
  const float* Wo  = (const float*)d_in[6];
  const float* Am  = (const float*)d_in[7];
  const float* Bm  = (const float*)d_in[8];
  const float* Win = (const float*)d_in[9];
  const float* Wup = (const float*)d_in[10];
  const float* Wdn = (const float*)d_in[11];
  float* out = (float*)d_out;
  (void)in_sizes; (void)n_in;

  const int T = 4096;
  const int Dm = 2048, F = 8192;
  const size_t MB = (size_t)1 << 20;

  const size_t need = 184 * MB;
  if (ws_size < need) {
    hipMemsetAsync(d_out, 0, (size_t)out_size * 4, stream);
    return;
  }
  char* base = (char*)d_ws;
  unsigned short* tb    = (unsigned short*)(base);
  unsigned short* wqkv  = (unsigned short*)(base);
  unsigned short* xb    = (unsigned short*)(base + 24 * MB);
  unsigned short* attnO = (unsigned short*)(base + 40 * MB);
  unsigned short* qkv   = (unsigned short*)(base + 64 * MB);
  unsigned short* win   = (unsigned short*)(base + 64 * MB);
  unsigned short* wo    = (unsigned short*)(base + 112 * MB);
  unsigned short* hb    = (unsigned short*)(base + 120 * MB);
  unsigned short* attn  = (unsigned short*)(base + 136 * MB);
  float*          cv    = (float*)(base + 136 * MB);
  unsigned short* wup   = (unsigned short*)(base + 152 * MB);
  unsigned short* wdn   = (unsigned short*)(base + 152 * MB);

  cvt_f32_bf16<<<2048, 256, 0, stream>>>(Wq, wqkv, Dm * Dm / 4);
  cvt_f32_bf16<<<2048, 256, 0, stream>>>(Wk, wqkv + (size_t)Dm * Dm, Dm * Dm / 4);
  cvt_f32_bf16<<<2048, 256, 0, stream>>>(Wv, wqkv + (size_t)2 * Dm * Dm, Dm * Dm / 4);
  cvt_f32_bf16<<<2048, 256, 0, stream>>>(Wo, wo, Dm * Dm / 4);
  rmsnorm_dual<<<T, 256, 0, stream>>>(hs, ln1, ln2, xb, hb);

  // QKV projection via 256^2 8-phase: grid 16 x 24 = 384
  gemm256<<<(T / 256) * (3 * Dm / 256), 512, 0, stream>>>(xb, wqkv, 3 * Dm, Dm, qkv);

  attn_fwd<<<dim3(32, 32), 256, 0, stream>>>(qkv, attn);

  gemm_bt<E_NONE><<<(T / 128) * (Dm / 128), 256, 0, stream>>>(
      attn, wo, Dm, Dm, attnO, nullptr, nullptr);

  modc<<<T / 4, 256, 0, stream>>>(attnO, hb, Am, cv);

  cvt_f32_bf16<<<2048, 256, 0, stream>>>(Win, win, F * Dm / 4);
  cvt_f32_bf16<<<2048, 256, 0, stream>>>(Wup, wup, F * Dm / 4);

  // fused gate/up via 256x128 8-phase: grid 16 x 64 = 1024
  gemm_mlp256<<<(T / 256) * (F / 128), 512, 0, stream>>>(hb, win, wup, cv, Bm, tb);

  cvt_f32_bf16<<<2048, 256, 0, stream>>>(Wdn, wdn, Dm * F / 4);
  gemm_bt<E_RES><<<(T / 128) * (Dm / 128), 256, 0, stream>>>(
      tb, wdn, Dm, F, nullptr, out, hs);
}

// Round 4
// 905.696 us; speedup vs baseline: 1.4566x; 1.2438x over previous
//
#include <hip/hip_runtime.h>

#define DI __device__ __forceinline__

typedef short s16x8 __attribute__((ext_vector_type(8)));
typedef float f32x4 __attribute__((ext_vector_type(4)));

typedef __attribute__((address_space(1))) const unsigned int as1_cuint;
typedef __attribute__((address_space(3))) unsigned int as3_uint;

DI unsigned short f2bf(float f) {
  union { float f; unsigned int u; } v; v.f = f;
  unsigned int r = v.u + 0x7fffu + ((v.u >> 16) & 1u);
  return (unsigned short)(r >> 16);
}
DI float bf2f(unsigned short b) {
  union { unsigned int u; float f; } v; v.u = ((unsigned int)b) << 16;
  return v.f;
}

DI void gl_lds16(const void* g, void* l) {
  __builtin_amdgcn_global_load_lds((as1_cuint*)g, (as3_uint*)l, 16, 0, 0);
}

DI void bar() {
  __builtin_amdgcn_sched_barrier(0);
  __builtin_amdgcn_s_barrier();
  __builtin_amdgcn_sched_barrier(0);
}
DI void s_vmcnt6() { asm volatile("s_waitcnt vmcnt(6)" ::: "memory"); }
DI void s_vmcnt0() { asm volatile("s_waitcnt vmcnt(0)" ::: "memory"); }

// stage one 128x64 bf16 half-tile (16 KiB) linearly into LDS; XOR-swizzle applied on
// the GLOBAL source (rule #21: linear dest + inverse-swizzled source). 512 threads.
DI void stage_half(const unsigned short* gb, size_t r0, int K, int kt,
                   unsigned short* lh, int tid) {
#pragma unroll
  for (int j = 0; j < 2; ++j) {
    int o = j * 8192 + tid * 16;  // byte offset in half-tile
    int row = o >> 7, cb = o & 127;
    int scb = cb ^ ((row & 7) << 4);
    gl_lds16(gb + (r0 + row) * (size_t)K + kt + (scb >> 1),
             lh + ((j * 8192 + (tid >> 6) * 1024) >> 1));
  }
}

// read one MFMA fragment (16B/lane) from a swizzled half-tile (64B rows)
DI s16x8 rd_frag(const unsigned short* lds, int baseE, int rwh, int kh, int lane) {
  int cb = kh * 64 + ((lane >> 4) << 4);
  int scb = cb ^ ((rwh & 7) << 4);
  return *(const s16x8*)&lds[baseE + rwh * 64 + (scb >> 1)];
}

// ---------------- fp32 -> bf16 convert ----------------
__global__ __launch_bounds__(256) void cvt_f32_bf16(const float* __restrict__ src,
                                                    unsigned short* __restrict__ dst, int n4) {
  int i = blockIdx.x * blockDim.x + threadIdx.x;
  int stride = gridDim.x * blockDim.x;
  for (; i < n4; i += stride) {
    float4 v = ((const float4*)src)[i];
    ((ushort4*)dst)[i] = make_ushort4(f2bf(v.x), f2bf(v.y), f2bf(v.z), f2bf(v.w));
  }
}

// ---------------- dual RMSNorm ----------------
__global__ __launch_bounds__(256) void rmsnorm_dual(const float* __restrict__ hs,
                                                    const float* __restrict__ w1,
                                                    const float* __restrict__ w2,
                                                    unsigned short* __restrict__ xo,
                                                    unsigned short* __restrict__ ho) {
  const int D = 2048;
  int t = blockIdx.x, tid = threadIdx.x;
  const float* row = hs + (size_t)t * D;
  float4 a = ((const float4*)row)[tid * 2];
  float4 b = ((const float4*)row)[tid * 2 + 1];
  float ss = a.x * a.x + a.y * a.y + a.z * a.z + a.w * a.w +
             b.x * b.x + b.y * b.y + b.z * b.z + b.w * b.w;
#pragma unroll
  for (int off = 32; off; off >>= 1) ss += __shfl_xor(ss, off);
  __shared__ float red[4];
  int wave = tid >> 6, lane = tid & 63;
  if (lane == 0) red[wave] = ss;
  __syncthreads();
  float tot = red[0] + red[1] + red[2] + red[3];
  float inv = rsqrtf(tot / (float)D + 1e-6f);
  int base = tid * 8;
  float vals[8] = {a.x, a.y, a.z, a.w, b.x, b.y, b.z, b.w};
  float4 w1a = ((const float4*)(w1 + base))[0];
  float4 w1b = ((const float4*)(w1 + base))[1];
  float4 w2a = ((const float4*)(w2 + base))[0];
  float4 w2b = ((const float4*)(w2 + base))[1];
  float w1v[8] = {w1a.x, w1a.y, w1a.z, w1a.w, w1b.x, w1b.y, w1b.z, w1b.w};
  float w2v[8] = {w2a.x, w2a.y, w2a.z, w2a.w, w2b.x, w2b.y, w2b.z, w2b.w};
  unsigned short ox[8], oh[8];
#pragma unroll
  for (int j = 0; j < 8; ++j) {
    float n = vals[j] * inv;
    ox[j] = f2bf(n * w1v[j]);
    oh[j] = f2bf(n * w2v[j]);
  }
  ushort4* xp = (ushort4*)(xo + (size_t)t * D + base);
  ushort4* hp = (ushort4*)(ho + (size_t)t * D + base);
  xp[0] = make_ushort4(ox[0], ox[1], ox[2], ox[3]);
  xp[1] = make_ushort4(ox[4], ox[5], ox[6], ox[7]);
  hp[0] = make_ushort4(oh[0], oh[1], oh[2], oh[3]);
  hp[1] = make_ushort4(oh[4], oh[5], oh[6], oh[7]);
}

// =========== 256x256 8-phase GEMM (T2+T3+T4+T5): C[M,N] = A @ Bt^T ===========
#define E_NONE 0
#define E_RES 3

template <int EPI>
__global__ __launch_bounds__(512, 2) void gemm256(
    const unsigned short* __restrict__ Amat, const unsigned short* __restrict__ Bt,
    int N, int K, unsigned short* __restrict__ Cbf, float* __restrict__ Cf,
    const float* __restrict__ Res) {
  __shared__ __align__(16) unsigned short lds[65536];
  int tid = threadIdx.x, lane = tid & 63;
  int w = tid >> 6, wm = w >> 2, wn = w & 3;
  int lr = lane & 15, lkh = lane >> 4;
  int nbn = N >> 8, nwg = gridDim.x, wg = blockIdx.x;
  int cpx = nwg >> 3;
  int swz = (wg & 7) * cpx + (wg >> 3);
  int tm = swz / nbn, tn = swz - tm * nbn;
  size_t m0 = (size_t)tm * 256, n0 = (size_t)tn * 256;
  int NT = K >> 6;

  auto stage = [&](int tau, int slot) {  // slot: 0=A0 1=A1 2=B0 3=B1
    if (tau >= NT) return;
    const unsigned short* gb = (slot >= 2) ? Bt : Amat;
    size_t r0 = (slot >= 2) ? (n0 + (size_t)(slot - 2) * 128) : (m0 + (size_t)slot * 128);
    stage_half(gb, r0, K, tau * 64, &lds[(tau & 1) * 32768 + slot * 8192], tid);
  };

  stage(0, 0); stage(0, 2); stage(0, 1); stage(0, 3);
  stage(1, 0); stage(1, 2); stage(1, 1);
  s_vmcnt6();
  bar();

  f32x4 acc[8][4] = {};
  s16x8 afr[4][2], bfr[2][2][2];

  for (int t = 0; t < NT; ++t) {
    int buf = (t & 1) * 32768;
    // p0: read A0+B0; stage B1(t+1)
#pragma unroll
    for (int mi = 0; mi < 4; ++mi)
#pragma unroll
      for (int kh = 0; kh < 2; ++kh)
        afr[mi][kh] = rd_frag(lds, buf + 0 * 8192, mi * 32 + wm * 16 + lr, kh, lane);
#pragma unroll
    for (int ni = 0; ni < 2; ++ni)
#pragma unroll
      for (int kh = 0; kh < 2; ++kh)
        bfr[0][ni][kh] = rd_frag(lds, buf + 2 * 8192, ni * 64 + wn * 16 + lr, kh, lane);
    stage(t + 1, 3);
    bar();
    __builtin_amdgcn_s_setprio(1);
#pragma unroll
    for (int mi = 0; mi < 4; ++mi)
#pragma unroll
      for (int ni = 0; ni < 2; ++ni)
#pragma unroll
        for (int kh = 0; kh < 2; ++kh)
          acc[mi][ni] = __builtin_amdgcn_mfma_f32_16x16x32_bf16(afr[mi][kh], bfr[0][ni][kh], acc[mi][ni], 0, 0, 0);
    __builtin_amdgcn_s_setprio(0);
    bar();
    // p1: read B1; stage A0(t+2)
#pragma unroll
    for (int ni = 0; ni < 2; ++ni)
#pragma unroll
      for (int kh = 0; kh < 2; ++kh)
        bfr[1][ni][kh] = rd_frag(lds, buf + 3 * 8192, ni * 64 + wn * 16 + lr, kh, lane);
    stage(t + 2, 0);
    bar();
    __builtin_amdgcn_s_setprio(1);
#pragma unroll
    for (int mi = 0; mi < 4; ++mi)
#pragma unroll
      for (int ni = 0; ni < 2; ++ni)
#pragma unroll
        for (int kh = 0; kh < 2; ++kh)
          acc[mi][2 + ni] = __builtin_amdgcn_mfma_f32_16x16x32_bf16(afr[mi][kh], bfr[1][ni][kh], acc[mi][2 + ni], 0, 0, 0);
    __builtin_amdgcn_s_setprio(0);
    bar();
    // p2: read A1; stage B0(t+2)
#pragma unroll
    for (int mi = 0; mi < 4; ++mi)
#pragma unroll
      for (int kh = 0; kh < 2; ++kh)
        afr[mi][kh] = rd_frag(lds, buf + 1 * 8192, mi * 32 + wm * 16 + lr, kh, lane);
    stage(t + 2, 2);
    bar();
    __builtin_amdgcn_s_setprio(1);
#pragma unroll
    for (int mi = 0; mi < 4; ++mi)
#pragma unroll
      for (int ni = 0; ni < 2; ++ni)
#pragma unroll
        for (int kh = 0; kh < 2; ++kh)
          acc[4 + mi][ni] = __builtin_amdgcn_mfma_f32_16x16x32_bf16(afr[mi][kh], bfr[0][ni][kh], acc[4 + mi][ni], 0, 0, 0);
    __builtin_amdgcn_s_setprio(0);
    bar();
    // p3: stage A1(t+2); boundary vmcnt
    stage(t + 2, 1);
    bar();
    __builtin_amdgcn_s_setprio(1);
#pragma unroll
    for (int mi = 0; mi < 4; ++mi)
#pragma unroll
      for (int ni = 0; ni < 2; ++ni)
#pragma unroll
        for (int kh = 0; kh < 2; ++kh)
          acc[4 + mi][2 + ni] = __builtin_amdgcn_mfma_f32_16x16x32_bf16(afr[mi][kh], bfr[1][ni][kh], acc[4 + mi][2 + ni], 0, 0, 0);
    __builtin_amdgcn_s_setprio(0);
    if (t < NT - 2) s_vmcnt6();
    else if (t == NT - 2) s_vmcnt0();
    bar();
  }

#pragma unroll
  for (int mh = 0; mh < 2; ++mh)
#pragma unroll
    for (int mi = 0; mi < 4; ++mi)
#pragma unroll
      for (int r = 0; r < 4; ++r) {
        size_t row = m0 + mh * 128 + mi * 32 + wm * 16 + lkh * 4 + r;
#pragma unroll
        for (int nh = 0; nh < 2; ++nh)
#pragma unroll
          for (int ni = 0; ni < 2; ++ni) {
            size_t col = n0 + nh * 128 + ni * 64 + wn * 16 + lr;
            float v = acc[mh * 4 + mi][nh * 2 + ni][r];
            if constexpr (EPI == E_RES) Cf[row * N + col] = Res[row * N + col] + v;
            else Cbf[row * N + col] = f2bf(v);
          }
      }
}

// ===== 256x128 8-phase fused MLP: Out = silu(H@Wg^T + c@Bsm) * (H@Wu^T) =====
__global__ __launch_bounds__(512, 2) void gemm_mlp256(
    const unsigned short* __restrict__ Hm, const unsigned short* __restrict__ Wg,
    const unsigned short* __restrict__ Wu,
    const float* __restrict__ cvec, const float* __restrict__ Bsm,
    unsigned short* __restrict__ Out) {
  const int N = 8192, K = 2048, NT = K >> 6;
  __shared__ __align__(16) unsigned short lds[65536];
  int tid = threadIdx.x, lane = tid & 63;
  int w = tid >> 6, wm = w >> 2, wn = w & 3;
  int lr = lane & 15, lkh = lane >> 4;
  int nbn = N >> 7, nwg = gridDim.x, wg = blockIdx.x;
  int cpx = nwg >> 3;
  int swz = (wg & 7) * cpx + (wg >> 3);
  int tm = swz / nbn, tn = swz - tm * nbn;
  size_t m0 = (size_t)tm * 256, n0 = (size_t)tn * 128;

  auto stage = [&](int tau, int slot) {
    if (tau >= NT) return;
    const unsigned short* gb = (slot == 2) ? Wg : (slot == 3) ? Wu : Hm;
    size_t r0 = (slot >= 2) ? n0 : (m0 + (size_t)slot * 128);
    stage_half(gb, r0, K, tau * 64, &lds[(tau & 1) * 32768 + slot * 8192], tid);
  };

  stage(0, 0); stage(0, 2); stage(0, 1); stage(0, 3);
  stage(1, 0); stage(1, 2); stage(1, 1);
  s_vmcnt6();
  bar();

  f32x4 ag[8][2] = {}, au[8][2] = {};
  s16x8 afr[4][2], bg[2][2], bu[2][2];

  for (int t = 0; t < NT; ++t) {
    int buf = (t & 1) * 32768;
#pragma unroll
    for (int mi = 0; mi < 4; ++mi)
#pragma unroll
      for (int kh = 0; kh < 2; ++kh)
        afr[mi][kh] = rd_frag(lds, buf + 0 * 8192, mi * 32 + wm * 16 + lr, kh, lane);
#pragma unroll
    for (int ni = 0; ni < 2; ++ni)
#pragma unroll
      for (int kh = 0; kh < 2; ++kh)
        bg[ni][kh] = rd_frag(lds, buf + 2 * 8192, ni * 64 + wn * 16 + lr, kh, lane);
    stage(t + 1, 3);
    bar();
    __builtin_amdgcn_s_setprio(1);
#pragma unroll
    for (int mi = 0; mi < 4; ++mi)
#pragma unroll
      for (int ni = 0; ni < 2; ++ni)
#pragma unroll
        for (int kh = 0; kh < 2; ++kh)
          ag[mi][ni] = __builtin_amdgcn_mfma_f32_16x16x32_bf16(afr[mi][kh], bg[ni][kh], ag[mi][ni], 0, 0, 0);
    __builtin_amdgcn_s_setprio(0);
    bar();
#pragma unroll
    for (int ni = 0; ni < 2; ++ni)
#pragma unroll
      for (int kh = 0; kh < 2; ++kh)
        bu[ni][kh] = rd_frag(lds, buf + 3 * 8192, ni * 64 + wn * 16 + lr, kh, lane);
    stage(t + 2, 0);
    bar();
    __builtin_amdgcn_s_setprio(1);
#pragma unroll
    for (int mi = 0; mi < 4; ++mi)
#pragma unroll
      for (int ni = 0; ni < 2; ++ni)
#pragma unroll
        for (int kh = 0; kh < 2; ++kh)
          au[mi][ni] = __builtin_amdgcn_mfma_f32_16x16x32_bf16(afr[mi][kh], bu[ni][kh], au[mi][ni], 0, 0, 0);
    __builtin_amdgcn_s_setprio(0);
    bar();
#pragma unroll
    for (int mi = 0; mi < 4; ++mi)
#pragma unroll
      for (int kh = 0; kh < 2; ++kh)
        afr[mi][kh] = rd_frag(lds, buf + 1 * 8192, mi * 32 + wm * 16 + lr, kh, lane);
    stage(t + 2, 2);
    bar();
    __builtin_amdgcn_s_setprio(1);
#pragma unroll
    for (int mi = 0; mi < 4; ++mi)
#pragma unroll
      for (int ni = 0; ni < 2; ++ni)
#pragma unroll
        for (int kh = 0; kh < 2; ++kh)
          ag[4 + mi][ni] = __builtin_amdgcn_mfma_f32_16x16x32_bf16(afr[mi][kh], bg[ni][kh], ag[4 + mi][ni], 0, 0, 0);
    __builtin_amdgcn_s_setprio(0);
    bar();
    stage(t + 2, 1);
    bar();
    __builtin_amdgcn_s_setprio(1);
#pragma unroll
    for (int mi = 0; mi < 4; ++mi)
#pragma unroll
      for (int ni = 0; ni < 2; ++ni)
#pragma unroll
        for (int kh = 0; kh < 2; ++kh)
          au[4 + mi][ni] = __builtin_amdgcn_mfma_f32_16x16x32_bf16(afr[mi][kh], bu[ni][kh], au[4 + mi][ni], 0, 0, 0);
    __builtin_amdgcn_s_setprio(0);
    if (t < NT - 2) s_vmcnt6();
    else if (t == NT - 2) s_vmcnt0();
    bar();
  }

  float* cl = (float*)lds;          // [256][16] f32
  float* bl = (float*)&lds[32768];  // [16][128] f32
#pragma unroll
  for (int j = 0; j < 2; ++j) {
    int fi = tid * 2 + j;
    ((float4*)cl)[fi] = ((const float4*)(cvec + m0 * 16))[fi];
  }
  {
    int fi = tid;
    ((float4*)bl)[fi] = *(const float4*)(Bsm + (size_t)(fi >> 5) * N + n0 + (fi & 31) * 4);
  }
  bar();

#pragma unroll
  for (int mh = 0; mh < 2; ++mh)
#pragma unroll
    for (int mi = 0; mi < 4; ++mi)
#pragma unroll
      for (int r = 0; r < 4; ++r) {
        int rr = mh * 128 + mi * 32 + wm * 16 + lkh * 4 + r;
        size_t row = m0 + rr;
#pragma unroll
        for (int ni = 0; ni < 2; ++ni) {
          int cc = ni * 64 + wn * 16 + lr;
          size_t col = n0 + cc;
          float s = 0.f;
#pragma unroll
          for (int jj = 0; jj < 16; ++jj) s += cl[rr * 16 + jj] * bl[jj * 128 + cc];
          float g = ag[mh * 4 + mi][ni][r] + s;
          float sig = 1.f / (1.f + __expf(-g));
          Out[row * N + col] = f2bf(g * sig * au[mh * 4 + mi][ni][r]);
        }
      }
}

// ---------- V transpose: vT[bh][d][k] = qkv[(b*2048+k)*6144 + 4096 + h*128 + d] ----------
__global__ __launch_bounds__(256) void vtrans(const unsigned short* __restrict__ qkv,
                                              unsigned short* __restrict__ vT) {
  __shared__ unsigned short t[64][72];
  int bh = blockIdx.z, b = bh >> 4, h = bh & 15;
  int k0 = blockIdx.x * 64, d0 = blockIdx.y * 64;
  int tid = threadIdx.x;
#pragma unroll
  for (int j = 0; j < 2; ++j) {
    int idx = tid + j * 256;
    int r = idx >> 3, c8 = (idx & 7) * 8;
    s16x8 v = *(const s16x8*)(qkv + ((size_t)(b * 2048 + k0 + r)) * 6144 + 4096 + h * 128 + d0 + c8);
#pragma unroll
    for (int e = 0; e < 8; ++e) t[r][c8 + e] = (unsigned short)v[e];
  }
  __syncthreads();
#pragma unroll
  for (int j = 0; j < 2; ++j) {
    int idx = tid + j * 256;
    int dr = idx >> 3, k8 = (idx & 7) * 8;
    s16x8 o;
#pragma unroll
    for (int e = 0; e < 8; ++e) o[e] = (short)t[k8 + e][dr];
    *(s16x8*)(vT + (size_t)bh * 262144 + (size_t)(d0 + dr) * 2048 + k0 + k8) = o;
  }
}

// ---------- causal flash attention v2: KVBLK=64, vT staging, balanced pair-pass ----------
// block: 256 thr (4 waves x 16 q-rows); pass0 qtile=qp, pass1 qtile=31-qp -> 33 tiles/block
__global__ __launch_bounds__(256, 2) void attn_fwd2(const unsigned short* __restrict__ qkv,
                                                    const unsigned short* __restrict__ vT,
                                                    unsigned short* __restrict__ attn) {
  const int LD = 6144;
  __shared__ __align__(16) unsigned short Kt[8192];  // [64 k][128 d], 256B rows, swz
  __shared__ __align__(16) unsigned short Vt[8192];  // [128 d][64 k], 128B rows, swz
  __shared__ __align__(16) unsigned short Pl[4096];  // 4 waves x [16 q][64 k], swz
  int tid = threadIdx.x, w = tid >> 6, lane = tid & 63;
  int lrow = lane & 15, g = lane >> 4;
  int qp = blockIdx.x, bh = blockIdx.y, b = bh >> 4, h = bh & 15;
  const unsigned short* Qb = qkv + (size_t)b * 2048 * LD + h * 128;
  const unsigned short* Kb = Qb + 2048;
  const unsigned short* vTb = vT + (size_t)bh * 262144;
  const float scale = 0.08838834764831845f;  // 1/sqrt(128)

#pragma unroll
  for (int pass = 0; pass < 2; ++pass) {
    int qtile = pass ? (31 - qp) : qp;
    int wq0 = qtile * 64 + w * 16;
    s16x8 qf[4];
#pragma unroll
    for (int kc = 0; kc < 4; ++kc)
      qf[kc] = *(const s16x8*)(Qb + (size_t)(wq0 + lrow) * LD + kc * 32 + g * 8);
    f32x4 ao[8] = {};
    float m_r[4], l_r[4];
#pragma unroll
    for (int r = 0; r < 4; ++r) { m_r[r] = -1e30f; l_r[r] = 0.f; }
    int nkt = qtile + 1;

    for (int kt = 0; kt < nkt; ++kt) {
      int k0 = kt * 64;
      bar();  // all waves done reading LDS of previous tile
      // stage K tile [64][128]: 4 x gl_lds16 per thread
#pragma unroll
      for (int j = 0; j < 4; ++j) {
        int o = j * 4096 + tid * 16;
        int row = o >> 8, cb = o & 255;
        int scb = cb ^ ((row & 7) << 4);
        gl_lds16(Kb + (size_t)(k0 + row) * LD + (scb >> 1), &Kt[(j * 4096 + w * 1024) >> 1]);
      }
      // stage V^T tile [128][64]
#pragma unroll
      for (int j = 0; j < 4; ++j) {
        int o = j * 4096 + tid * 16;
        int row = o >> 7, cb = o & 127;
        int scb = cb ^ ((row & 7) << 4);
        gl_lds16(vTb + (size_t)row * 2048 + k0 + (scb >> 1), &Vt[(j * 4096 + w * 1024) >> 1]);
      }
      s_vmcnt0();
      bar();
      // QK^T: S[16q][64k] per wave
      f32x4 sa[4] = {};
#pragma unroll
      for (int ni = 0; ni < 4; ++ni)
#pragma unroll
        for (int kc = 0; kc < 4; ++kc) {
          int row = ni * 16 + lrow;
          int cb = kc * 64 + g * 16;
          int scb = cb ^ ((row & 7) << 4);
          s16x8 kf = *(const s16x8*)&Kt[row * 128 + (scb >> 1)];
          sa[ni] = __builtin_amdgcn_mfma_f32_16x16x32_bf16(qf[kc], kf, sa[ni], 0, 0, 0);
        }
      // scale + causal mask (mask only needed on diagonal tile)
      if (k0 + 63 > wq0) {
#pragma unroll
        for (int ni = 0; ni < 4; ++ni)
#pragma unroll
          for (int r = 0; r < 4; ++r) {
            int q_idx = wq0 + g * 4 + r, k_idx = k0 + ni * 16 + lrow;
            float sv = sa[ni][r] * scale;
            sa[ni][r] = (k_idx > q_idx) ? -1e30f : sv;
          }
      } else {
#pragma unroll
        for (int ni = 0; ni < 4; ++ni)
#pragma unroll
          for (int r = 0; r < 4; ++r) sa[ni][r] *= scale;
      }
      // online softmax over 64 k (regs x 16 lanes)
      float mt[4];
#pragma unroll
      for (int r = 0; r < 4; ++r)
        mt[r] = fmaxf(fmaxf(sa[0][r], sa[1][r]), fmaxf(sa[2][r], sa[3][r]));
#pragma unroll
      for (int r = 0; r < 4; ++r)
#pragma unroll
        for (int off = 8; off; off >>= 1) mt[r] = fmaxf(mt[r], __shfl_xor(mt[r], off));
      float al[4];
#pragma unroll
      for (int r = 0; r < 4; ++r) {
        float mn = fmaxf(m_r[r], mt[r]);
        al[r] = __expf(m_r[r] - mn);
        m_r[r] = mn;
      }
      float rs[4] = {0.f, 0.f, 0.f, 0.f};
#pragma unroll
      for (int ni = 0; ni < 4; ++ni)
#pragma unroll
        for (int r = 0; r < 4; ++r) {
          float p = __expf(sa[ni][r] - m_r[r]);
          rs[r] += p;
          int q = g * 4 + r, k = ni * 16 + lrow;
          Pl[w * 1024 + q * 64 + (k ^ ((q & 7) << 3))] = f2bf(p);
        }
#pragma unroll
      for (int r = 0; r < 4; ++r) {
#pragma unroll
        for (int off = 8; off; off >>= 1) rs[r] += __shfl_xor(rs[r], off);
        l_r[r] = l_r[r] * al[r] + rs[r];
      }
#pragma unroll
      for (int df = 0; df < 8; ++df)
#pragma unroll
        for (int r = 0; r < 4; ++r) ao[df][r] *= al[r];
      asm volatile("s_waitcnt lgkmcnt(0)" ::: "memory");
      __builtin_amdgcn_sched_barrier(0);
      // PV: A-frag = P (swz), B-frag = vT rows (swz)
      s16x8 pa[2];
#pragma unroll
      for (int ks = 0; ks < 2; ++ks)
        pa[ks] = *(const s16x8*)&Pl[w * 1024 + lrow * 64 + ((ks * 32 + g * 8) ^ ((lrow & 7) << 3))];
#pragma unroll
      for (int df = 0; df < 8; ++df) {
#pragma unroll
        for (int ks = 0; ks < 2; ++ks) {
          int row = df * 16 + lrow;
          int cb = ks * 64 + g * 16;
          int scb = cb ^ ((row & 7) << 4);
          s16x8 vf = *(const s16x8*)&Vt[row * 64 + (scb >> 1)];
          ao[df] = __builtin_amdgcn_mfma_f32_16x16x32_bf16(pa[ks], vf, ao[df], 0, 0, 0);
        }
      }
    }
    // write pass output
#pragma unroll
    for (int df = 0; df < 8; ++df)
#pragma unroll
      for (int r = 0; r < 4; ++r) {
        int q = wq0 + g * 4 + r;
        float v = ao[df][r] / l_r[r];
        attn[((size_t)b * 2048 + q) * 2048 + h * 128 + df * 16 + lrow] = f2bf(v);
      }
    bar();  // protect LDS before pass 2 restages
  }
}

// ---------------- modc ----------------
__global__ __launch_bounds__(256) void modc(const unsigned short* __restrict__ attnO,
                                            const unsigned short* __restrict__ h,
                                            const float* __restrict__ A,
                                            float* __restrict__ cvec) {
  const int D = 2048;
  int t = blockIdx.x * 4 + (threadIdx.x >> 6);
  int lane = threadIdx.x & 63;
  float aA[16] = {}, aH[16] = {};
  for (int i = 0; i < D / 64; ++i) {
    int d = i * 64 + lane;
    float av = bf2f(attnO[(size_t)t * D + d]);
    float hv = bf2f(h[(size_t)t * D + d]);
    const float* ar = A + (size_t)d * 16;
#pragma unroll
    for (int j = 0; j < 16; ++j) {
      float a = ar[j];
      aA[j] += av * a;
      aH[j] += hv * a;
    }
  }
#pragma unroll
  for (int j = 0; j < 16; ++j) {
#pragma unroll
    for (int off = 32; off; off >>= 1) {
      aA[j] += __shfl_xor(aA[j], off);
      aH[j] += __shfl_xor(aH[j], off);
    }
  }
#pragma unroll
  for (int j = 0; j < 16; ++j)
    if (lane == j) cvec[(size_t)t * 16 + j] = 0.1f * tanhf(aA[j]) * aH[j];
}

extern "C" void kernel_launch(void* const* d_in, const int* in_sizes, int n_in,
                              void* d_out, int out_size, void* d_ws, size_t ws_size,
                              hipStream_t stream) {
  const float* hs  = (const float*)d_in[0];
  const float* ln1 = (const float*)d_in[1];
  const float* ln2 = (const float*)d_in[2];
  const float* Wq  = (const float*)d_in[3];
  const float* Wk  = (const float*)d_in[4];
  const float* Wv  = (const float*)d_in[5];
  const float* Wo  = (const float*)d_in[6];
  const float* Am  = (const float*)d_in[7];
  const float* Bm  = (const float*)d_in[8];
  const float* Win = (const float*)d_in[9];
  const float* Wup = (const float*)d_in[10];
  const float* Wdn = (const float*)d_in[11];
  float* out = (float*)d_out;
  (void)in_sizes; (void)n_in;

  const int T = 4096;
  const int Dm = 2048, F = 8192;
  const size_t MB = (size_t)1 << 20;

  const size_t need = 184 * MB;
  if (ws_size < need) {
    hipMemsetAsync(d_out, 0, (size_t)out_size * 4, stream);
    return;
  }
  // Lifetime-aliased layout (184 MiB):
  //  [0,64)   tb (MLP) | earlier: wqkv@0(24) -> vT@0(16, after QKV-gemm), xb@24(16), attnO@40(16)
  //  [64,120) qkv@64(48) | later: win@64(32)
  //  [112,120) wo  (inside qkv? no: wo@112 while qkv occupies [64,112) -- 48MB = qkv)
  //  [120,136) hb ; [136,152) attn | cv ; [152,184) wup -> wdn
  char* base = (char*)d_ws;
  unsigned short* tb    = (unsigned short*)(base);
  unsigned short* wqkv  = (unsigned short*)(base);
  unsigned short* vT    = (unsigned short*)(base);
  unsigned short* xb    = (unsigned short*)(base + 24 * MB);
  unsigned short* attnO = (unsigned short*)(base + 40 * MB);
  unsigned short* qkv   = (unsigned short*)(base + 64 * MB);
  unsigned short* win   = (unsigned short*)(base + 64 * MB);
  unsigned short* wo    = (unsigned short*)(base + 112 * MB);
  unsigned short* hb    = (unsigned short*)(base + 120 * MB);
  unsigned short* attn  = (unsigned short*)(base + 136 * MB);
  float*          cv    = (float*)(base + 136 * MB);
  unsigned short* wup   = (unsigned short*)(base + 152 * MB);
  unsigned short* wdn   = (unsigned short*)(base + 152 * MB);

  cvt_f32_bf16<<<2048, 256, 0, stream>>>(Wq, wqkv, Dm * Dm / 4);
  cvt_f32_bf16<<<2048, 256, 0, stream>>>(Wk, wqkv + (size_t)Dm * Dm, Dm * Dm / 4);
  cvt_f32_bf16<<<2048, 256, 0, stream>>>(Wv, wqkv + (size_t)2 * Dm * Dm, Dm * Dm / 4);
  cvt_f32_bf16<<<2048, 256, 0, stream>>>(Wo, wo, Dm * Dm / 4);
  rmsnorm_dual<<<T, 256, 0, stream>>>(hs, ln1, ln2, xb, hb);

  // QKV projection: grid 16x24 = 384
  gemm256<E_NONE><<<(T / 256) * (3 * Dm / 256), 512, 0, stream>>>(
      xb, wqkv, 3 * Dm, Dm, qkv, nullptr, nullptr);

  // V transpose into vT (overwrites dead wqkv region)
  vtrans<<<dim3(32, 2, 32), 256, 0, stream>>>(qkv, vT);

  attn_fwd2<<<dim3(16, 32), 256, 0, stream>>>(qkv, vT, attn);

  // O projection: grid 16x8 = 128
  gemm256<E_NONE><<<(T / 256) * (Dm / 256), 512, 0, stream>>>(
      attn, wo, Dm, Dm, attnO, nullptr, nullptr);

  modc<<<T / 4, 256, 0, stream>>>(attnO, hb, Am, cv);

  cvt_f32_bf16<<<2048, 256, 0, stream>>>(Win, win, F * Dm / 4);
  cvt_f32_bf16<<<2048, 256, 0, stream>>>(Wup, wup, F * Dm / 4);

  // fused gate/up: grid 16x64 = 1024
  gemm_mlp256<<<(T / 256) * (F / 128), 512, 0, stream>>>(hb, win, wup, cv, Bm, tb);

  cvt_f32_bf16<<<2048, 256, 0, stream>>>(Wdn, wdn, Dm * F / 4);
  // down + residual: grid 16x8 = 128, K=8192
  gemm256<E_RES><<<(T / 256) * (Dm / 256), 512, 0, stream>>>(
      tb, wdn, Dm, F, nullptr, out, hs);
}

// Round 5
// 792.047 us; speedup vs baseline: 1.6656x; 1.1435x over previous
//
#include <hip/hip_runtime.h>

#define DI __device__ __forceinline__

typedef short s16x8 __attribute__((ext_vector_type(8)));
typedef float f32x4 __attribute__((ext_vector_type(4)));

typedef __attribute__((address_space(1))) const unsigned int as1_cuint;
typedef __attribute__((address_space(3))) unsigned int as3_uint;

DI unsigned short f2bf(float f) {
  union { float f; unsigned int u; } v; v.f = f;
  unsigned int r = v.u + 0x7fffu + ((v.u >> 16) & 1u);
  return (unsigned short)(r >> 16);
}
DI float bf2f(unsigned short b) {
  union { unsigned int u; float f; } v; v.u = ((unsigned int)b) << 16;
  return v.f;
}

DI void gl_lds16(const void* g, void* l) {
  __builtin_amdgcn_global_load_lds((as1_cuint*)g, (as3_uint*)l, 16, 0, 0);
}

DI void bar() {
  __builtin_amdgcn_sched_barrier(0);
  __builtin_amdgcn_s_barrier();
  __builtin_amdgcn_sched_barrier(0);
}
DI void vm0() { asm volatile("s_waitcnt vmcnt(0)" ::: "memory"); }
DI void vm2() { asm volatile("s_waitcnt vmcnt(2)" ::: "memory"); }
DI void vm4() { asm volatile("s_waitcnt vmcnt(4)" ::: "memory"); }
DI void vm6() { asm volatile("s_waitcnt vmcnt(6)" ::: "memory"); }

#define MFMA __builtin_amdgcn_mfma_f32_16x16x32_bf16

// ---------------- fp32 -> bf16 convert ----------------
__global__ __launch_bounds__(256) void cvt_f32_bf16(const float* __restrict__ src,
                                                    unsigned short* __restrict__ dst, int n4) {
  int i = blockIdx.x * blockDim.x + threadIdx.x;
  int stride = gridDim.x * blockDim.x;
  for (; i < n4; i += stride) {
    float4 v = ((const float4*)src)[i];
    ((ushort4*)dst)[i] = make_ushort4(f2bf(v.x), f2bf(v.y), f2bf(v.z), f2bf(v.w));
  }
}

// ---------------- dual RMSNorm ----------------
__global__ __launch_bounds__(256) void rmsnorm_dual(const float* __restrict__ hs,
                                                    const float* __restrict__ w1,
                                                    const float* __restrict__ w2,
                                                    unsigned short* __restrict__ xo,
                                                    unsigned short* __restrict__ ho) {
  const int D = 2048;
  int t = blockIdx.x, tid = threadIdx.x;
  const float* row = hs + (size_t)t * D;
  float4 a = ((const float4*)row)[tid * 2];
  float4 b = ((const float4*)row)[tid * 2 + 1];
  float ss = a.x * a.x + a.y * a.y + a.z * a.z + a.w * a.w +
             b.x * b.x + b.y * b.y + b.z * b.z + b.w * b.w;
#pragma unroll
  for (int off = 32; off; off >>= 1) ss += __shfl_xor(ss, off);
  __shared__ float red[4];
  int wave = tid >> 6, lane = tid & 63;
  if (lane == 0) red[wave] = ss;
  __syncthreads();
  float tot = red[0] + red[1] + red[2] + red[3];
  float inv = rsqrtf(tot / (float)D + 1e-6f);
  int base = tid * 8;
  float vals[8] = {a.x, a.y, a.z, a.w, b.x, b.y, b.z, b.w};
  float4 w1a = ((const float4*)(w1 + base))[0];
  float4 w1b = ((const float4*)(w1 + base))[1];
  float4 w2a = ((const float4*)(w2 + base))[0];
  float4 w2b = ((const float4*)(w2 + base))[1];
  float w1v[8] = {w1a.x, w1a.y, w1a.z, w1a.w, w1b.x, w1b.y, w1b.z, w1b.w};
  float w2v[8] = {w2a.x, w2a.y, w2a.z, w2a.w, w2b.x, w2b.y, w2b.z, w2b.w};
  unsigned short ox[8], oh[8];
#pragma unroll
  for (int j = 0; j < 8; ++j) {
    float n = vals[j] * inv;
    ox[j] = f2bf(n * w1v[j]);
    oh[j] = f2bf(n * w2v[j]);
  }
  ushort4* xp = (ushort4*)(xo + (size_t)t * D + base);
  ushort4* hp = (ushort4*)(ho + (size_t)t * D + base);
  xp[0] = make_ushort4(ox[0], ox[1], ox[2], ox[3]);
  xp[1] = make_ushort4(ox[4], ox[5], ox[6], ox[7]);
  hp[0] = make_ushort4(oh[0], oh[1], oh[2], oh[3]);
  hp[1] = make_ushort4(oh[4], oh[5], oh[6], oh[7]);
}

// ======== 256x128 2-phase GEMM (address-hoisted): C[M,N] = A[M,K] @ Bt[N,K]^T ========
// 8 waves (2M x 4N), per-wave out 128x32. LDS 96KB: [buf][slot A0,A1,B][8192 elems].
// All staging targets tile t+1 (other buffer) -> race-free by double-buffer.
#define E_NONE 0
#define E_RES 3

template <int EPI>
__global__ __launch_bounds__(512, 2) void gemm_n128(
    const unsigned short* __restrict__ Amat, const unsigned short* __restrict__ Bt,
    int N, int K, int NT,
    unsigned short* __restrict__ Cbf, float* __restrict__ Cf,
    const float* __restrict__ Res) {
  __shared__ __align__(16) unsigned short lds[49152];
  int tid = threadIdx.x, lane = tid & 63;
  int w = tid >> 6, wm = w >> 2, wn = w & 3;
  int lr = lane & 15, g = lane >> 4;
  int nbn = N >> 7, nwg = gridDim.x, wg = blockIdx.x;
  int cpx = nwg >> 3;
  int swz = (wg & 7) * cpx + (wg >> 3);
  int tm = swz / nbn, tn = swz - tm * nbn;
  size_t m0 = (size_t)tm * 256, n0 = (size_t)tn * 128;

  // hoisted LDS frag byte-offsets (slot-relative)
  int boffA[4][2], boffB[2][2];
#pragma unroll
  for (int mi = 0; mi < 4; ++mi)
#pragma unroll
    for (int kh = 0; kh < 2; ++kh) {
      int row = mi * 32 + wm * 16 + lr;
      boffA[mi][kh] = row * 128 + ((kh * 64 + g * 16) ^ ((row & 7) << 4));
    }
#pragma unroll
  for (int ni = 0; ni < 2; ++ni)
#pragma unroll
    for (int kh = 0; kh < 2; ++kh) {
      int row = ni * 64 + wn * 16 + lr;
      boffB[ni][kh] = row * 128 + ((kh * 64 + g * 16) ^ ((row & 7) << 4));
    }
  const char* ldsb = (const char*)lds;

  // hoisted staging pointers: thread covers (row=tid/8, 16B chunk (tid&7), swizzled)
  int srow = tid >> 3;
  int scb = ((tid & 7) * 16) ^ ((srow & 7) << 4);
  const unsigned short* pA0 = Amat + (m0 + srow) * (size_t)K + (scb >> 1);
  const unsigned short* pA1 = pA0 + (size_t)128 * K;
  const unsigned short* pB  = Bt + (n0 + srow) * (size_t)K + (scb >> 1);
  const size_t jst = (size_t)64 * K;  // second half of a 128-row unit
  int dst = w * 512;                  // LDS dest element offset (j=0)

  f32x4 acc[8][2] = {};

  auto stg = [&](const unsigned short* p, int BUF, int SLOT) {
    gl_lds16(p, &lds[BUF * 24576 + SLOT * 8192 + dst]);
    gl_lds16(p + jst, &lds[BUF * 24576 + SLOT * 8192 + 4096 + dst]);
  };

  // prologue: tile0 {A0,B,A1}
  stg(pA0, 0, 0); stg(pB, 0, 2); stg(pA1, 0, 1);
  pA0 += 64; pA1 += 64; pB += 64;
  vm2();
  bar();

  auto tile = [&](int t, int BUF) {
    s16x8 afr[4][2], bfr[2][2];
    // ---- p0: read A0+B frags; stage A0,B (t+1)
#pragma unroll
    for (int mi = 0; mi < 4; ++mi)
#pragma unroll
      for (int kh = 0; kh < 2; ++kh)
        afr[mi][kh] = *(const s16x8*)(ldsb + BUF * 49152 + 0 * 16384 + boffA[mi][kh]);
#pragma unroll
    for (int ni = 0; ni < 2; ++ni)
#pragma unroll
      for (int kh = 0; kh < 2; ++kh)
        bfr[ni][kh] = *(const s16x8*)(ldsb + BUF * 49152 + 2 * 16384 + boffB[ni][kh]);
    if (t + 1 < NT) { stg(pA0, BUF ^ 1, 0); stg(pB, BUF ^ 1, 2); }
    bar();
    __builtin_amdgcn_s_setprio(1);
#pragma unroll
    for (int mi = 0; mi < 4; ++mi)
#pragma unroll
      for (int ni = 0; ni < 2; ++ni)
#pragma unroll
        for (int kh = 0; kh < 2; ++kh)
          acc[mi][ni] = MFMA(afr[mi][kh], bfr[ni][kh], acc[mi][ni], 0, 0, 0);
    __builtin_amdgcn_s_setprio(0);
    if (t + 1 < NT) vm4(); else vm0();
    bar();
    // ---- p1: read A1 frags; stage A1(t+1)
#pragma unroll
    for (int mi = 0; mi < 4; ++mi)
#pragma unroll
      for (int kh = 0; kh < 2; ++kh)
        afr[mi][kh] = *(const s16x8*)(ldsb + BUF * 49152 + 1 * 16384 + boffA[mi][kh]);
    if (t + 1 < NT) stg(pA1, BUF ^ 1, 1);
    bar();
    __builtin_amdgcn_s_setprio(1);
#pragma unroll
    for (int mi = 0; mi < 4; ++mi)
#pragma unroll
      for (int ni = 0; ni < 2; ++ni)
#pragma unroll
        for (int kh = 0; kh < 2; ++kh)
          acc[4 + mi][ni] = MFMA(afr[mi][kh], bfr[ni][kh], acc[4 + mi][ni], 0, 0, 0);
    __builtin_amdgcn_s_setprio(0);
    if (t + 1 < NT) vm2();
    bar();
    pA0 += 64; pA1 += 64; pB += 64;
  };

  for (int t = 0; t < NT; t += 2) { tile(t, 0); tile(t + 1, 1); }

#pragma unroll
  for (int mh = 0; mh < 2; ++mh)
#pragma unroll
    for (int mi = 0; mi < 4; ++mi)
#pragma unroll
      for (int r = 0; r < 4; ++r) {
        size_t row = m0 + mh * 128 + mi * 32 + wm * 16 + g * 4 + r;
#pragma unroll
        for (int ni = 0; ni < 2; ++ni) {
          size_t col = n0 + ni * 64 + wn * 16 + lr;
          float v = acc[mh * 4 + mi][ni][r];
          if constexpr (EPI == E_RES) Cf[row * N + col] = Res[row * N + col] + v;
          else Cbf[row * N + col] = f2bf(v);
        }
      }
}

// ===== 256x128 4-phase fused MLP (hoisted): Out = silu(H@Wg^T + c@Bsm) * (H@Wu^T) =====
__global__ __launch_bounds__(512, 2) void gemm_mlp256(
    const unsigned short* __restrict__ Hm, const unsigned short* __restrict__ Wg,
    const unsigned short* __restrict__ Wu,
    const float* __restrict__ cvec, const float* __restrict__ Bsm,
    unsigned short* __restrict__ Out) {
  const int N = 8192, K = 2048, NT = 32;
  __shared__ __align__(16) unsigned short lds[65536];  // [buf][slot A0,A1,Bg,Bu][8192]
  int tid = threadIdx.x, lane = tid & 63;
  int w = tid >> 6, wm = w >> 2, wn = w & 3;
  int lr = lane & 15, g = lane >> 4;
  int nbn = N >> 7, nwg = gridDim.x, wg = blockIdx.x;
  int cpx = nwg >> 3;
  int swz = (wg & 7) * cpx + (wg >> 3);
  int tm = swz / nbn, tn = swz - tm * nbn;
  size_t m0 = (size_t)tm * 256, n0 = (size_t)tn * 128;

  int boffA[4][2], boffB[2][2];
#pragma unroll
  for (int mi = 0; mi < 4; ++mi)
#pragma unroll
    for (int kh = 0; kh < 2; ++kh) {
      int row = mi * 32 + wm * 16 + lr;
      boffA[mi][kh] = row * 128 + ((kh * 64 + g * 16) ^ ((row & 7) << 4));
    }
#pragma unroll
  for (int ni = 0; ni < 2; ++ni)
#pragma unroll
    for (int kh = 0; kh < 2; ++kh) {
      int row = ni * 64 + wn * 16 + lr;
      boffB[ni][kh] = row * 128 + ((kh * 64 + g * 16) ^ ((row & 7) << 4));
    }
  const char* ldsb = (const char*)lds;

  int srow = tid >> 3;
  int scb = ((tid & 7) * 16) ^ ((srow & 7) << 4);
  const unsigned short* pA0 = Hm + (m0 + srow) * (size_t)K + (scb >> 1);
  const unsigned short* pA1 = pA0 + (size_t)128 * K;
  const unsigned short* pBg = Wg + (n0 + srow) * (size_t)K + (scb >> 1);
  const unsigned short* pBu = Wu + (n0 + srow) * (size_t)K + (scb >> 1);
  const size_t jst = (size_t)64 * K;
  int dst = w * 512;

  f32x4 ag[8][2] = {}, au[8][2] = {};

  auto stg = [&](const unsigned short* p, int BUF, int SLOT) {
    gl_lds16(p, &lds[BUF * 32768 + SLOT * 8192 + dst]);
    gl_lds16(p + jst, &lds[BUF * 32768 + SLOT * 8192 + 4096 + dst]);
  };

  // prologue: tile0 {A0,Bg,Bu,A1}; wait A0,Bg
  stg(pA0, 0, 0); stg(pBg, 0, 2); stg(pBu, 0, 3); stg(pA1, 0, 1);
  pA0 += 64; pA1 += 64; pBg += 64; pBu += 64;
  vm4();
  bar();

  auto tile = [&](int t, int BUF) {
    s16x8 afr[4][2], bg[2][2], bu[2][2];
    // p0: read A0+Bg; stage A0,Bg(t+1)
#pragma unroll
    for (int mi = 0; mi < 4; ++mi)
#pragma unroll
      for (int kh = 0; kh < 2; ++kh)
        afr[mi][kh] = *(const s16x8*)(ldsb + BUF * 65536 + 0 * 16384 + boffA[mi][kh]);
#pragma unroll
    for (int ni = 0; ni < 2; ++ni)
#pragma unroll
      for (int kh = 0; kh < 2; ++kh)
        bg[ni][kh] = *(const s16x8*)(ldsb + BUF * 65536 + 2 * 16384 + boffB[ni][kh]);
    if (t + 1 < NT) { stg(pA0, BUF ^ 1, 0); stg(pBg, BUF ^ 1, 2); }
    bar();
    __builtin_amdgcn_s_setprio(1);
#pragma unroll
    for (int mi = 0; mi < 4; ++mi)
#pragma unroll
      for (int ni = 0; ni < 2; ++ni)
#pragma unroll
        for (int kh = 0; kh < 2; ++kh)
          ag[mi][ni] = MFMA(afr[mi][kh], bg[ni][kh], ag[mi][ni], 0, 0, 0);
    __builtin_amdgcn_s_setprio(0);
    if (t + 1 < NT) vm6(); else vm2();
    bar();
    // p1: read Bu; stage Bu(t+1)
#pragma unroll
    for (int ni = 0; ni < 2; ++ni)
#pragma unroll
      for (int kh = 0; kh < 2; ++kh)
        bu[ni][kh] = *(const s16x8*)(ldsb + BUF * 65536 + 3 * 16384 + boffB[ni][kh]);
    if (t + 1 < NT) stg(pBu, BUF ^ 1, 3);
    bar();
    __builtin_amdgcn_s_setprio(1);
#pragma unroll
    for (int mi = 0; mi < 4; ++mi)
#pragma unroll
      for (int ni = 0; ni < 2; ++ni)
#pragma unroll
        for (int kh = 0; kh < 2; ++kh)
          au[mi][ni] = MFMA(afr[mi][kh], bu[ni][kh], au[mi][ni], 0, 0, 0);
    __builtin_amdgcn_s_setprio(0);
    if (t + 1 < NT) vm6(); else vm0();
    bar();
    // p2: read A1; stage A1(t+1)
#pragma unroll
    for (int mi = 0; mi < 4; ++mi)
#pragma unroll
      for (int kh = 0; kh < 2; ++kh)
        afr[mi][kh] = *(const s16x8*)(ldsb + BUF * 65536 + 1 * 16384 + boffA[mi][kh]);
    if (t + 1 < NT) stg(pA1, BUF ^ 1, 1);
    bar();
    __builtin_amdgcn_s_setprio(1);
#pragma unroll
    for (int mi = 0; mi < 4; ++mi)
#pragma unroll
      for (int ni = 0; ni < 2; ++ni)
#pragma unroll
        for (int kh = 0; kh < 2; ++kh)
          ag[4 + mi][ni] = MFMA(afr[mi][kh], bg[ni][kh], ag[4 + mi][ni], 0, 0, 0);
    __builtin_amdgcn_s_setprio(0);
    bar();
    // p3: MFMA up mh1
    __builtin_amdgcn_s_setprio(1);
#pragma unroll
    for (int mi = 0; mi < 4; ++mi)
#pragma unroll
      for (int ni = 0; ni < 2; ++ni)
#pragma unroll
        for (int kh = 0; kh < 2; ++kh)
          au[4 + mi][ni] = MFMA(afr[mi][kh], bu[ni][kh], au[4 + mi][ni], 0, 0, 0);
    __builtin_amdgcn_s_setprio(0);
    if (t + 1 < NT) vm4();
    bar();
    pA0 += 64; pA1 += 64; pBg += 64; pBu += 64;
  };

  for (int t = 0; t < NT; t += 2) { tile(t, 0); tile(t + 1, 1); }

  // epilogue: c-tile 256x16 f32 + Bsm-tile 16x128 f32 into reused LDS
  float* cl = (float*)lds;          // [256][16]
  float* bl = (float*)&lds[32768];  // [16][128]
#pragma unroll
  for (int j = 0; j < 2; ++j) {
    int fi = tid * 2 + j;
    ((float4*)cl)[fi] = ((const float4*)(cvec + m0 * 16))[fi];
  }
  {
    int fi = tid;
    ((float4*)bl)[fi] = *(const float4*)(Bsm + (size_t)(fi >> 5) * N + n0 + (fi & 31) * 4);
  }
  bar();

#pragma unroll
  for (int mh = 0; mh < 2; ++mh)
#pragma unroll
    for (int mi = 0; mi < 4; ++mi)
#pragma unroll
      for (int r = 0; r < 4; ++r) {
        int rr = mh * 128 + mi * 32 + wm * 16 + g * 4 + r;
        size_t row = m0 + rr;
#pragma unroll
        for (int ni = 0; ni < 2; ++ni) {
          int cc = ni * 64 + wn * 16 + lr;
          size_t col = n0 + cc;
          float s = 0.f;
#pragma unroll
          for (int jj = 0; jj < 16; ++jj) s += cl[rr * 16 + jj] * bl[jj * 128 + cc];
          float gg = ag[mh * 4 + mi][ni][r] + s;
          float sig = 1.f / (1.f + __expf(-gg));
          Out[row * N + col] = f2bf(gg * sig * au[mh * 4 + mi][ni][r]);
        }
      }
}

// ---------- V transpose: vT[bh][d][k] ----------
__global__ __launch_bounds__(256) void vtrans(const unsigned short* __restrict__ qkv,
                                              unsigned short* __restrict__ vT) {
  __shared__ unsigned short t[64][72];
  int bh = blockIdx.z, b = bh >> 4, h = bh & 15;
  int k0 = blockIdx.x * 64, d0 = blockIdx.y * 64;
  int tid = threadIdx.x;
#pragma unroll
  for (int j = 0; j < 2; ++j) {
    int idx = tid + j * 256;
    int r = idx >> 3, c8 = (idx & 7) * 8;
    s16x8 v = *(const s16x8*)(qkv + ((size_t)(b * 2048 + k0 + r)) * 6144 + 4096 + h * 128 + d0 + c8);
#pragma unroll
    for (int e = 0; e < 8; ++e) t[r][c8 + e] = (unsigned short)v[e];
  }
  __syncthreads();
#pragma unroll
  for (int j = 0; j < 2; ++j) {
    int idx = tid + j * 256;
    int dr = idx >> 3, k8 = (idx & 7) * 8;
    s16x8 o;
#pragma unroll
    for (int e = 0; e < 8; ++e) o[e] = (short)t[k8 + e][dr];
    *(s16x8*)(vT + (size_t)bh * 262144 + (size_t)(d0 + dr) * 2048 + k0 + k8) = o;
  }
}

// ---------- causal flash attention: KVBLK=64, vT staging, balanced pair-pass ----------
__global__ __launch_bounds__(256, 2) void attn_fwd2(const unsigned short* __restrict__ qkv,
                                                    const unsigned short* __restrict__ vT,
                                                    unsigned short* __restrict__ attn) {
  const int LD = 6144;
  __shared__ __align__(16) unsigned short Kt[8192];
  __shared__ __align__(16) unsigned short Vt[8192];
  __shared__ __align__(16) unsigned short Pl[4096];
  int tid = threadIdx.x, w = tid >> 6, lane = tid & 63;
  int lrow = lane & 15, g = lane >> 4;
  int qp = blockIdx.x, bh = blockIdx.y, b = bh >> 4, h = bh & 15;
  const unsigned short* Qb = qkv + (size_t)b * 2048 * LD + h * 128;
  const unsigned short* Kb = Qb + 2048;
  const unsigned short* vTb = vT + (size_t)bh * 262144;
  const float scale = 0.08838834764831845f;

#pragma unroll
  for (int pass = 0; pass < 2; ++pass) {
    int qtile = pass ? (31 - qp) : qp;
    int wq0 = qtile * 64 + w * 16;
    s16x8 qf[4];
#pragma unroll
    for (int kc = 0; kc < 4; ++kc)
      qf[kc] = *(const s16x8*)(Qb + (size_t)(wq0 + lrow) * LD + kc * 32 + g * 8);
    f32x4 ao[8] = {};
    float m_r[4], l_r[4];
#pragma unroll
    for (int r = 0; r < 4; ++r) { m_r[r] = -1e30f; l_r[r] = 0.f; }
    int nkt = qtile + 1;

    for (int kt = 0; kt < nkt; ++kt) {
      int k0 = kt * 64;
      bar();
#pragma unroll
      for (int j = 0; j < 4; ++j) {
        int o = j * 4096 + tid * 16;
        int row = o >> 8, cb = o & 255;
        int scb = cb ^ ((row & 7) << 4);
        gl_lds16(Kb + (size_t)(k0 + row) * LD + (scb >> 1), &Kt[(j * 4096 + w * 1024) >> 1]);
      }
#pragma unroll
      for (int j = 0; j < 4; ++j) {
        int o = j * 4096 + tid * 16;
        int row = o >> 7, cb = o & 127;
        int scb = cb ^ ((row & 7) << 4);
        gl_lds16(vTb + (size_t)row * 2048 + k0 + (scb >> 1), &Vt[(j * 4096 + w * 1024) >> 1]);
      }
      vm0();
      bar();
      f32x4 sa[4] = {};
#pragma unroll
      for (int ni = 0; ni < 4; ++ni)
#pragma unroll
        for (int kc = 0; kc < 4; ++kc) {
          int row = ni * 16 + lrow;
          int cb = kc * 64 + g * 16;
          int scb = cb ^ ((row & 7) << 4);
          s16x8 kf = *(const s16x8*)&Kt[row * 128 + (scb >> 1)];
          sa[ni] = MFMA(qf[kc], kf, sa[ni], 0, 0, 0);
        }
      if (k0 + 63 > wq0) {
#pragma unroll
        for (int ni = 0; ni < 4; ++ni)
#pragma unroll
          for (int r = 0; r < 4; ++r) {
            int q_idx = wq0 + g * 4 + r, k_idx = k0 + ni * 16 + lrow;
            float sv = sa[ni][r] * scale;
            sa[ni][r] = (k_idx > q_idx) ? -1e30f : sv;
          }
      } else {
#pragma unroll
        for (int ni = 0; ni < 4; ++ni)
#pragma unroll
          for (int r = 0; r < 4; ++r) sa[ni][r] *= scale;
      }
      float mt[4];
#pragma unroll
      for (int r = 0; r < 4; ++r)
        mt[r] = fmaxf(fmaxf(sa[0][r], sa[1][r]), fmaxf(sa[2][r], sa[3][r]));
#pragma unroll
      for (int r = 0; r < 4; ++r)
#pragma unroll
        for (int off = 8; off; off >>= 1) mt[r] = fmaxf(mt[r], __shfl_xor(mt[r], off));
      float al[4];
#pragma unroll
      for (int r = 0; r < 4; ++r) {
        float mn = fmaxf(m_r[r], mt[r]);
        al[r] = __expf(m_r[r] - mn);
        m_r[r] = mn;
      }
      float rs[4] = {0.f, 0.f, 0.f, 0.f};
#pragma unroll
      for (int ni = 0; ni < 4; ++ni)
#pragma unroll
        for (int r = 0; r < 4; ++r) {
          float p = __expf(sa[ni][r] - m_r[r]);
          rs[r] += p;
          int q = g * 4 + r, k = ni * 16 + lrow;
          Pl[w * 1024 + q * 64 + (k ^ ((q & 7) << 3))] = f2bf(p);
        }
#pragma unroll
      for (int r = 0; r < 4; ++r) {
#pragma unroll
        for (int off = 8; off; off >>= 1) rs[r] += __shfl_xor(rs[r], off);
        l_r[r] = l_r[r] * al[r] + rs[r];
      }
#pragma unroll
      for (int df = 0; df < 8; ++df)
#pragma unroll
        for (int r = 0; r < 4; ++r) ao[df][r] *= al[r];
      asm volatile("s_waitcnt lgkmcnt(0)" ::: "memory");
      __builtin_amdgcn_sched_barrier(0);
      s16x8 pa[2];
#pragma unroll
      for (int ks = 0; ks < 2; ++ks)
        pa[ks] = *(const s16x8*)&Pl[w * 1024 + lrow * 64 + ((ks * 32 + g * 8) ^ ((lrow & 7) << 3))];
#pragma unroll
      for (int df = 0; df < 8; ++df) {
#pragma unroll
        for (int ks = 0; ks < 2; ++ks) {
          int row = df * 16 + lrow;
          int cb = ks * 64 + g * 16;
          int scb = cb ^ ((row & 7) << 4);
          s16x8 vf = *(const s16x8*)&Vt[row * 64 + (scb >> 1)];
          ao[df] = MFMA(pa[ks], vf, ao[df], 0, 0, 0);
        }
      }
    }
#pragma unroll
    for (int df = 0; df < 8; ++df)
#pragma unroll
      for (int r = 0; r < 4; ++r) {
        int q = wq0 + g * 4 + r;
        float v = ao[df][r] / l_r[r];
        attn[((size_t)b * 2048 + q) * 2048 + h * 128 + df * 16 + lrow] = f2bf(v);
      }
    bar();
  }
}

// ---------------- modc ----------------
__global__ __launch_bounds__(256) void modc(const unsigned short* __restrict__ attnO,
                                            const unsigned short* __restrict__ h,
                                            const float* __restrict__ A,
                                            float* __restrict__ cvec) {
  const int D = 2048;
  int t = blockIdx.x * 4 + (threadIdx.x >> 6);
  int lane = threadIdx.x & 63;
  float aA[16] = {}, aH[16] = {};
  for (int i = 0; i < D / 64; ++i) {
    int d = i * 64 + lane;
    float av = bf2f(attnO[(size_t)t * D + d]);
    float hv = bf2f(h[(size_t)t * D + d]);
    const float* ar = A + (size_t)d * 16;
#pragma unroll
    for (int j = 0; j < 16; ++j) {
      float a = ar[j];
      aA[j] += av * a;
      aH[j] += hv * a;
    }
  }
#pragma unroll
  for (int j = 0; j < 16; ++j) {
#pragma unroll
    for (int off = 32; off; off >>= 1) {
      aA[j] += __shfl_xor(aA[j], off);
      aH[j] += __shfl_xor(aH[j], off);
    }
  }
#pragma unroll
  for (int j = 0; j < 16; ++j)
    if (lane == j) cvec[(size_t)t * 16 + j] = 0.1f * tanhf(aA[j]) * aH[j];
}

extern "C" void kernel_launch(void* const* d_in, const int* in_sizes, int n_in,
                              void* d_out, int out_size, void* d_ws, size_t ws_size,
                              hipStream_t stream) {
  const float* hs  = (const float*)d_in[0];
  const float* ln1 = (const float*)d_in[1];
  const float* ln2 = (const float*)d_in[2];
  const float* Wq  = (const float*)d_in[3];
  const float* Wk  = (const float*)d_in[4];
  const float* Wv  = (const float*)d_in[5];
  const float* Wo  = (const float*)d_in[6];
  const float* Am  = (const float*)d_in[7];
  const float* Bm  = (const float*)d_in[8];
  const float* Win = (const float*)d_in[9];
  const float* Wup = (const float*)d_in[10];
  const float* Wdn = (const float*)d_in[11];
  float* out = (float*)d_out;
  (void)in_sizes; (void)n_in;

  const int T = 4096;
  const int Dm = 2048, F = 8192;
  const size_t MB = (size_t)1 << 20;

  const size_t need = 184 * MB;
  if (ws_size < need) {
    hipMemsetAsync(d_out, 0, (size_t)out_size * 4, stream);
    return;
  }
  char* base = (char*)d_ws;
  unsigned short* tb    = (unsigned short*)(base);
  unsigned short* wqkv  = (unsigned short*)(base);
  unsigned short* vT    = (unsigned short*)(base);
  unsigned short* xb    = (unsigned short*)(base + 24 * MB);
  unsigned short* attnO = (unsigned short*)(base + 40 * MB);
  unsigned short* qkv   = (unsigned short*)(base + 64 * MB);
  unsigned short* win   = (unsigned short*)(base + 64 * MB);
  unsigned short* wo    = (unsigned short*)(base + 112 * MB);
  unsigned short* hb    = (unsigned short*)(base + 120 * MB);
  unsigned short* attn  = (unsigned short*)(base + 136 * MB);
  float*          cv    = (float*)(base + 136 * MB);
  unsigned short* wup   = (unsigned short*)(base + 152 * MB);
  unsigned short* wdn   = (unsigned short*)(base + 152 * MB);

  cvt_f32_bf16<<<2048, 256, 0, stream>>>(Wq, wqkv, Dm * Dm / 4);
  cvt_f32_bf16<<<2048, 256, 0, stream>>>(Wk, wqkv + (size_t)Dm * Dm, Dm * Dm / 4);
  cvt_f32_bf16<<<2048, 256, 0, stream>>>(Wv, wqkv + (size_t)2 * Dm * Dm, Dm * Dm / 4);
  cvt_f32_bf16<<<2048, 256, 0, stream>>>(Wo, wo, Dm * Dm / 4);
  rmsnorm_dual<<<T, 256, 0, stream>>>(hs, ln1, ln2, xb, hb);

  // QKV projection: 16 x 48 = 768 blocks (3 exact rounds)
  gemm_n128<E_NONE><<<(T / 256) * (3 * Dm / 128), 512, 0, stream>>>(
      xb, wqkv, 3 * Dm, Dm, Dm / 64, qkv, nullptr, nullptr);

  vtrans<<<dim3(32, 2, 32), 256, 0, stream>>>(qkv, vT);
  attn_fwd2<<<dim3(16, 32), 256, 0, stream>>>(qkv, vT, attn);

  // O projection: 16 x 16 = 256 blocks (1 exact round)
  gemm_n128<E_NONE><<<(T / 256) * (Dm / 128), 512, 0, stream>>>(
      attn, wo, Dm, Dm, Dm / 64, attnO, nullptr, nullptr);

  modc<<<T / 4, 256, 0, stream>>>(attnO, hb, Am, cv);

  cvt_f32_bf16<<<2048, 256, 0, stream>>>(Win, win, F * Dm / 4);
  cvt_f32_bf16<<<2048, 256, 0, stream>>>(Wup, wup, F * Dm / 4);

  // fused gate/up: 16 x 64 = 1024 blocks (4 exact rounds)
  gemm_mlp256<<<(T / 256) * (F / 128), 512, 0, stream>>>(hb, win, wup, cv, Bm, tb);

  cvt_f32_bf16<<<2048, 256, 0, stream>>>(Wdn, wdn, Dm * F / 4);
  // down + residual: 16 x 16 = 256 blocks (1 exact round), K=8192
  gemm_n128<E_RES><<<(T / 256) * (Dm / 128), 512, 0, stream>>>(
      tb, wdn, Dm, F, F / 64, nullptr, out, hs);
}